// Round 10
// baseline (658.610 us; speedup 1.0000x reference)
//
#include <hip/hip_runtime.h>

// ---------------------------------------------------------------------------
// SemanticMemoryLatentSpace, fully factored (see R7 header).
// R9: ABLATION ROUND. Real scan = R8 loop (no prelude), bit-identical.
// Four co-launched 128-step ablation variants write to throwaway scratch;
// their per-dispatch durations in rocprof attribute the per-round stall:
//   scan_a0: full loop, 128 steps (baseline quantum)
//   scan_a1: lag chain + q maintenance + u/qc broadcasts removed
//   scan_a2: wave_umax64 tree replaced by single readlane (chain probe)
//   scan_a3: global prefetch + LDS column reads removed (memory probe)
// ---------------------------------------------------------------------------

#define A_BOOSTF 0.012247448713915891f // 1.5*alpha (growth==0 always)

template <int CTRL>
__device__ __forceinline__ float dpp_f(float x) {
  return __int_as_float(
      __builtin_amdgcn_mov_dpp(__float_as_int(x), CTRL, 0xf, 0xf, true));
}
template <int CTRL>
__device__ __forceinline__ unsigned dpp_u(unsigned x) {
  return (unsigned)__builtin_amdgcn_mov_dpp((int)x, CTRL, 0xf, 0xf, true);
}
__device__ __forceinline__ float rdlane_f(float x, int l) {
  return __int_as_float(__builtin_amdgcn_readlane(__float_as_int(x), l));
}
__device__ __forceinline__ unsigned rdlane_u(unsigned x, int l) {
  return (unsigned)__builtin_amdgcn_readlane((int)x, l);
}
__device__ __forceinline__ float wave_sum64(float v) {
  v += dpp_f<0xB1>(v);
  v += dpp_f<0x4E>(v);
  v += dpp_f<0x124>(v);
  v += dpp_f<0x128>(v);
  return (rdlane_f(v, 0) + rdlane_f(v, 16)) + (rdlane_f(v, 32) + rdlane_f(v, 48));
}
__device__ __forceinline__ unsigned sortable(float v) {
  unsigned u = __float_as_uint(v);
  return u ^ (unsigned)(((int)u >> 31) | 0x80000000);
}
__device__ __forceinline__ float unsortable(unsigned x) {
  unsigned u = (x & 0x80000000u) ? (x ^ 0x80000000u) : ~x;
  return __uint_as_float(u);
}
__device__ __forceinline__ unsigned wave_umax64(unsigned v) {
  v = max(v, dpp_u<0xB1>(v));
  v = max(v, dpp_u<0x4E>(v));
  v = max(v, dpp_u<0x124>(v));
  v = max(v, dpp_u<0x128>(v));
  return max(max(rdlane_u(v, 0), rdlane_u(v, 16)),
             max(rdlane_u(v, 32), rdlane_u(v, 48)));
}

#define SELCOL(rowregs, cj, out)                                   \
  {                                                                \
    const int _g = (cj) >> 6, _l = (cj) & 63;                      \
    float _s = rowregs[0];                                         \
    _s = (_g == 1) ? rowregs[1] : _s;                              \
    _s = (_g == 2) ? rowregs[2] : _s;                              \
    _s = (_g == 3) ? rowregs[3] : _s;                              \
    out = rdlane_f(_s, _l);                                        \
  }

// ---------------- generic 32x32-tile fp32 GEMMs -----------------------------
__global__ __launch_bounds__(256) void gemm_nt(const float* __restrict__ A,
                                               const float* __restrict__ B,
                                               float* __restrict__ C,
                                               int N, int K) {
  __shared__ float As[32][33];
  __shared__ float Bs[32][33];
  int bx = blockIdx.x, by = blockIdx.y;
  int tid = threadIdx.x;
  int tx = tid & 15, ty = tid >> 4;
  float a00 = 0.f, a01 = 0.f, a10 = 0.f, a11 = 0.f;
  for (int k0 = 0; k0 < K; k0 += 32) {
    for (int l = tid; l < 1024; l += 256) {
      int r = l >> 5, c = l & 31;
      As[r][c] = A[(by * 32 + r) * K + k0 + c];
      Bs[r][c] = B[(bx * 32 + r) * K + k0 + c];
    }
    __syncthreads();
#pragma unroll
    for (int k = 0; k < 32; ++k) {
      float x0 = As[2 * ty][k], x1 = As[2 * ty + 1][k];
      float y0 = Bs[2 * tx][k], y1 = Bs[2 * tx + 1][k];
      a00 += x0 * y0; a01 += x0 * y1; a10 += x1 * y0; a11 += x1 * y1;
    }
    __syncthreads();
  }
  int i = by * 32 + 2 * ty, jj = bx * 32 + 2 * tx;
  C[i * N + jj] = a00;           C[i * N + jj + 1] = a01;
  C[(i + 1) * N + jj] = a10;     C[(i + 1) * N + jj + 1] = a11;
}

__global__ __launch_bounds__(256) void gemm_nn(const float* __restrict__ A,
                                               const float* __restrict__ B,
                                               float* __restrict__ C,
                                               int N, int K) {
  __shared__ float As[32][33];
  __shared__ float Bs[32][33];
  int bx = blockIdx.x, by = blockIdx.y;
  int tid = threadIdx.x;
  int tx = tid & 15, ty = tid >> 4;
  float a00 = 0.f, a01 = 0.f, a10 = 0.f, a11 = 0.f;
  for (int k0 = 0; k0 < K; k0 += 32) {
    for (int l = tid; l < 1024; l += 256) {
      int r = l >> 5, c = l & 31;
      As[r][c] = A[(by * 32 + r) * K + k0 + c];
      Bs[r][c] = B[(k0 + r) * N + bx * 32 + c];
    }
    __syncthreads();
#pragma unroll
    for (int k = 0; k < 32; ++k) {
      float x0 = As[2 * ty][k], x1 = As[2 * ty + 1][k];
      float y0 = Bs[k][2 * tx], y1 = Bs[k][2 * tx + 1];
      a00 += x0 * y0; a01 += x0 * y1; a10 += x1 * y0; a11 += x1 * y1;
    }
    __syncthreads();
  }
  int i = by * 32 + 2 * ty, jj = bx * 32 + 2 * tx;
  C[i * N + jj] = a00;           C[i * N + jj + 1] = a01;
  C[(i + 1) * N + jj] = a10;     C[(i + 1) * N + jj + 1] = a11;
}

__global__ __launch_bounds__(256) void final_gemm(const float* __restrict__ G,
                                                  const float* __restrict__ E,
                                                  const float* __restrict__ M0,
                                                  const float* __restrict__ W,
                                                  const float* __restrict__ gS,
                                                  float* __restrict__ out) {
  __shared__ float As[32][33];
  __shared__ float Bs[32][33];
  int bx = blockIdx.x, by = blockIdx.y;
  int tid = threadIdx.x;
  int tx = tid & 15, ty = tid >> 4;
  float a00 = 0.f, a01 = 0.f, a10 = 0.f, a11 = 0.f;
  for (int k0 = 0; k0 < 512; k0 += 32) {
    for (int l = tid; l < 1024; l += 256) {
      int r = l >> 5, c = l & 31;
      As[r][c] = G[(by * 32 + r) * 512 + k0 + c] * W[k0 + c];
      Bs[r][c] = E[(k0 + r) * 384 + bx * 32 + c];
    }
    __syncthreads();
#pragma unroll
    for (int k = 0; k < 32; ++k) {
      float x0 = As[2 * ty][k], x1 = As[2 * ty + 1][k];
      float y0 = Bs[k][2 * tx], y1 = Bs[k][2 * tx + 1];
      a00 += x0 * y0; a01 += x0 * y1; a10 += x1 * y0; a11 += x1 * y1;
    }
    __syncthreads();
  }
  float gv = gS[0];
  int i = by * 32 + 2 * ty, jj = bx * 32 + 2 * tx;
  out[i * 384 + jj]         = gv * M0[i * 384 + jj]         + a00;
  out[i * 384 + jj + 1]     = gv * M0[i * 384 + jj + 1]     + a01;
  out[(i + 1) * 384 + jj]     = gv * M0[(i + 1) * 384 + jj]     + a10;
  out[(i + 1) * 384 + jj + 1] = gv * M0[(i + 1) * 384 + jj + 1] + a11;
}

__global__ __launch_bounds__(256) void prep_kernel(const float* __restrict__ E,
                                                   const float* __restrict__ M0,
                                                   const float* __restrict__ K0,
                                                   float* __restrict__ u,
                                                   float* __restrict__ Kpart) {
  __shared__ double wr[4];
  int b = blockIdx.x;
  int tid = threadIdx.x, lane = tid & 63, wv = tid >> 6;
  if (b < 128) {
    int row = b * 4 + wv;
    const float4* e4 = (const float4*)(E + row * 384);
    const float4* m4 = (const float4*)(M0 + row * 384);
    float p = 0.f;
    for (int i = lane; i < 96; i += 64) {
      float4 a = e4[i], bb = m4[i];
      p += a.x * bb.x + a.y * bb.y + a.z * bb.z + a.w * bb.w;
    }
#pragma unroll
    for (int off = 32; off; off >>= 1) p += __shfl_down(p, off);
    if (lane == 0) u[row] = p;
  } else {
    int cb = b - 128;
    const float* p = K0 + cb * 2304 + tid * 9;
    double acc = 0.0;
#pragma unroll
    for (int i = 0; i < 9; ++i) { double v = (double)p[i]; acc += v * v; }
#pragma unroll
    for (int off = 32; off; off >>= 1) acc += __shfl_down(acc, off);
    if (lane == 0) wr[wv] = acc;
    __syncthreads();
    if (tid == 0) Kpart[cb] = (float)(wr[0] + wr[1] + wr[2] + wr[3]);
  }
}

// ---------------- scan body: templated for ablation ------------------------
// ABL: 0 = full; 1 = no lag chain / q / u; 2 = no max tree; 3 = no memory.
template <int ABL, int TSTEPS>
__device__ __forceinline__ void scan_body(const float* __restrict__ G,
                                          const float* __restrict__ u,
                                          const float* __restrict__ Kpart,
                                          float* __restrict__ Wout,
                                          float* __restrict__ gOut) {
  __shared__ float RAW[128 * 257];
  __shared__ float4 SLOT[512];
  __shared__ float u_sh[512];

  const int lane = threadIdx.x;
  const int ro0 = lane * 257, ro1 = (lane + 64) * 257;

  ((float4*)u_sh)[lane] = ((const float4*)u)[lane];
  ((float4*)u_sh)[lane + 64] = ((const float4*)u)[lane + 64];

  float d0 = 1.f, d1 = 1.f, cn0 = 0.f, cn1 = 0.f, s0 = 0.f, s1 = 0.f;
  float n2 = wave_sum64(Kpart[lane]);
  float g = 1.f, ginv = 1.f;
  float q[4] = {0.f, 0.f, 0.f, 0.f};
  int nact = 0;

  float4 z4 = {0.f, 0.f, 0.f, 0.f};
  for (int i = lane; i < 8224; i += 64) ((float4*)RAW)[i] = z4;

  float gr[4][4], pr[4][4];
#pragma unroll
  for (int k = 0; k < 4; ++k)
#pragma unroll
    for (int m = 0; m < 4; ++m) {
      gr[k][m] = G[k * 512 + m * 64 + lane];
      pr[k][m] = G[(4 + k) * 512 + m * 64 + lane];
    }
  float r0[4] = {0.f, 0.f, 0.f, 0.f}, r1[4] = {0.f, 0.f, 0.f, 0.f};

  for (int t = 0; t < TSTEPS; t += 4) {
    const int c = t & 255;
    if (TSTEPS > 256 && t == 256) {
      for (int i = lane; i < 8224; i += 64) ((float4*)RAW)[i] = z4;
#pragma unroll
      for (int m = 0; m < 4; ++m) q[m] = 0.f;
      __builtin_amdgcn_sched_barrier(0);
      const float* Gb = G + 256;
      float A[4][4], Bv[4][4];
      float4 SA[4], SB[4];
#pragma unroll
      for (int j = 0; j < 4; ++j) {
#pragma unroll
        for (int m = 0; m < 4; ++m) A[j][m] = Gb[j * 512 + m * 64 + lane];
        SA[j] = SLOT[j];
      }
      for (int s = 0; s < 256; s += 8) {
#pragma unroll
        for (int j = 0; j < 4; ++j) {
#pragma unroll
          for (int m = 0; m < 4; ++m)
            Bv[j][m] = Gb[(s + 4 + j) * 512 + m * 64 + lane];
          SB[j] = SLOT[s + 4 + j];
        }
#pragma unroll
        for (int j = 0; j < 4; ++j) {
          float bh = SA[j].x, wh = SA[j].y;
          int id = __float_as_int(SA[j].z);
#pragma unroll
          for (int m = 0; m < 4; ++m) {
            atomicAdd(&RAW[id * 257 + m * 64 + lane], bh * A[j][m]);
            q[m] += wh * A[j][m] * A[j][m];
          }
        }
        if (s + 8 < 256) {
#pragma unroll
          for (int j = 0; j < 4; ++j) {
#pragma unroll
            for (int m = 0; m < 4; ++m)
              A[j][m] = Gb[(s + 8 + j) * 512 + m * 64 + lane];
            SA[j] = SLOT[s + 8 + j];
          }
        }
#pragma unroll
        for (int j = 0; j < 4; ++j) {
          float bh = SB[j].x, wh = SB[j].y;
          int id = __float_as_int(SB[j].z);
#pragma unroll
          for (int m = 0; m < 4; ++m) {
            atomicAdd(&RAW[id * 257 + m * 64 + lane], bh * Bv[j][m]);
            q[m] += wh * Bv[j][m] * Bv[j][m];
          }
        }
      }
      __builtin_amdgcn_sched_barrier(0);
#pragma unroll
      for (int k = 0; k < 4; ++k) { r0[k] = RAW[ro0 + k]; r1[k] = RAW[ro1 + k]; }
      __builtin_amdgcn_sched_barrier(0);
    }

    float prn[4][4];
    if constexpr (ABL != 3) {
      const int tb = (t + 8 < 512) ? (t + 8) : 508;
      const int nb2 = tb & ~255;
#pragma unroll
      for (int k = 0; k < 4; ++k) {
        const int row = (t + 8 + k < 512) ? (t + 8 + k) : 511;
#pragma unroll
        for (int m = 0; m < 4; ++m)
          prn[k][m] = G[row * 512 + nb2 + m * 64 + lane];
      }
    } else {
#pragma unroll
      for (int k = 0; k < 4; ++k)
#pragma unroll
        for (int m = 0; m < 4; ++m)
          prn[k][m] = __builtin_fmaf(gr[k][m], 1.000001f, pr[k][m]);
    }

    float4 uu = {0.f, 0.f, 0.f, 0.f};
    if constexpr (ABL != 1) uu = *(const float4*)&u_sh[t];

    float tr[4], ren[4], qc[4] = {0.f, 0.f, 0.f, 0.f};
#pragma unroll
    for (int k = 0; k < 4; ++k) {
      SELCOL(gr[k], c + k, tr[k]);
      if constexpr (ABL != 1) {
        const int _g = (c + k) >> 6, _l = (c + k) & 63;
        float _s = q[0];
        _s = (_g == 1) ? q[1] : _s;
        _s = (_g == 2) ? q[2] : _s;
        _s = (_g == 3) ? q[3] : _s;
        qc[k] = rdlane_f(_s, _l);
      }
      ren[k] = __builtin_amdgcn_rcpf(__builtin_amdgcn_sqrtf(tr[k]));
    }
    float gx01, gx02, gx03, gx12, gx13, gx23;
    SELCOL(gr[0], c + 1, gx01); SELCOL(gr[0], c + 2, gx02);
    SELCOL(gr[0], c + 3, gx03); SELCOL(gr[1], c + 2, gx12);
    SELCOL(gr[1], c + 3, gx13); SELCOL(gr[2], c + 3, gx23);

    float bnewA[4], novA[4];
    int idxA[4];

#define STEP(K, RPATCH)                                                        \
    {                                                                          \
      float v0 = (lane < nact) ? s0 * ren[K] * r0[K] : -2.f;                   \
      float v1 = (lane + 64 < nact) ? s1 * ren[K] * r1[K] : -2.f;              \
      unsigned pk0 = (sortable(v0) & ~127u) | (unsigned)(127 - lane);          \
      unsigned pk1 = (sortable(v1) & ~127u) | (unsigned)(63 - lane);           \
      unsigned P;                                                              \
      if constexpr (ABL == 2) {                                                \
        P = rdlane_u(max(pk0, pk1), (t + K) & 63);                             \
      } else {                                                                 \
        P = wave_umax64(max(pk0, pk1));                                        \
      }                                                                        \
      int imax = 127 - (int)(P & 127u);                                        \
      float M = unsortable(P & ~127u);                                         \
      float nov = (nact == 0) ? 1.f : fminf(1.f, fmaxf(0.f, 1.f - M * M));     \
      int create = (nov > 0.7f && nact < 100) ? 1 : 0;                         \
      const int idxs = create ? nact : imax;                                   \
      const int cl = idxs & 63, hi = idxs >> 6;                                \
      float dcA = create ? 1.f : 0.95f * d0;                                   \
      float dcB = create ? 1.f : 0.95f * d1;                                   \
      float ccA = create ? tr[K]                                               \
                         : (0.9025f * cn0 + 0.095f * (d0 * r0[K]) + 0.0025f * tr[K]); \
      float ccB = create ? tr[K]                                               \
                         : (0.9025f * cn1 + 0.095f * (d1 * r1[K]) + 0.0025f * tr[K]); \
      float scA = dcA * __builtin_amdgcn_rcpf(__builtin_amdgcn_sqrtf(ccA));    \
      float scB = dcB * __builtin_amdgcn_rcpf(__builtin_amdgcn_sqrtf(ccB));    \
      bool own0 = (lane == cl) && (hi == 0);                                   \
      bool own1 = (lane == cl) && (hi == 1);                                   \
      d0 = own0 ? dcA : d0; cn0 = own0 ? ccA : cn0; s0 = own0 ? scA : s0;      \
      d1 = own1 ? dcB : d1; cn1 = own1 ? ccB : cn1; s1 = own1 ? scB : s1;      \
      float bnew = create ? 1.f                                                \
                          : 0.05f * __builtin_amdgcn_rcpf(                     \
                                        rdlane_f(hi ? dcB : dcA, cl));         \
      nact += create;                                                          \
      float pb0 = own0 ? bnew : 0.f, pb1 = own1 ? bnew : 0.f;                  \
      RPATCH                                                                   \
      bnewA[K] = bnew; novA[K] = nov; idxA[K] = idxs;                          \
      _Pragma("unroll")                                                        \
      for (int m = 0; m < 4; ++m)                                              \
        if (m * 64 + 63 >= c)                                                  \
          atomicAdd(&RAW[idxs * 257 + m * 64 + lane], bnew * gr[K][m]);        \
    }

    STEP(0, { r0[1] += pb0 * gx01; r1[1] += pb1 * gx01;
              r0[2] += pb0 * gx02; r1[2] += pb1 * gx02;
              r0[3] += pb0 * gx03; r1[3] += pb1 * gx03; })
    STEP(1, { r0[2] += pb0 * gx12; r1[2] += pb1 * gx12;
              r0[3] += pb0 * gx13; r1[3] += pb1 * gx13; })
    STEP(2, { r0[3] += pb0 * gx23; r1[3] += pb1 * gx23; })
    STEP(3, {})
#undef STEP

    if constexpr (ABL != 3) {
      if (((t + 4) & 255) != 0) {
        const int c4 = c + 4;
#pragma unroll
        for (int k = 0; k < 4; ++k) {
          r0[k] = RAW[ro0 + c4 + k];
          r1[k] = RAW[ro1 + c4 + k];
        }
      }
    }
    __builtin_amdgcn_sched_barrier(0);

    float whA[4];
    if constexpr (ABL != 1) {
      float um[4] = {uu.x, uu.y, uu.z, uu.w};
      float qeff1 = qc[1], qeff2 = qc[2], qeff3 = qc[3];
#pragma unroll
      for (int m = 0; m < 4; ++m) {
        float qe = (m == 0) ? qc[0] : ((m == 1) ? qeff1 : ((m == 2) ? qeff2 : qeff3));
        float iw = novA[m] * __builtin_amdgcn_sqrtf(novA[m]);
        float psc = 384.0f * __builtin_amdgcn_rcpf(fmaxf(tr[m], 1e-8f));
        float ccf = A_BOOSTF * iw * psc;
        float qv = g * (um[m] + qe);
        float n2n = n2 + 2.f * ccf * qv + ccf * ccf * tr[m] * tr[m];
        float kn = __builtin_amdgcn_sqrtf(n2n);
        float fct = (kn > 50.f) ? 50.f * __builtin_amdgcn_rcpf(kn) : 1.f;
        float fiv = (kn > 50.f) ? kn * 0.02f : 1.f;
        whA[m] = ccf * ginv;
        n2 = n2n * fct * fct; g *= fct; ginv *= fiv;
        if (m == 0) {
          qeff1 += whA[0] * gx01 * gx01;
          qeff2 += whA[0] * gx02 * gx02;
          qeff3 += whA[0] * gx03 * gx03;
        } else if (m == 1) {
          qeff2 += whA[1] * gx12 * gx12;
          qeff3 += whA[1] * gx13 * gx13;
        } else if (m == 2) {
          qeff3 += whA[2] * gx23 * gx23;
        }
      }
#pragma unroll
      for (int m = 0; m < 4; ++m)
#pragma unroll
        for (int k = 0; k < 4; ++k) q[m] += whA[k] * gr[k][m] * gr[k][m];
    } else {
#pragma unroll
      for (int m = 0; m < 4; ++m) whA[m] = bnewA[m];
    }

    if (lane == 0) {
#pragma unroll
      for (int k = 0; k < 4; ++k) {
        float4 rec = {bnewA[k], whA[k], __int_as_float(idxA[k]), 0.f};
        SLOT[t + k] = rec;
      }
    }

#pragma unroll
    for (int k = 0; k < 4; ++k)
#pragma unroll
      for (int m = 0; m < 4; ++m) { gr[k][m] = pr[k][m]; pr[k][m] = prn[k][m]; }
  }

  for (int s2 = lane; s2 < TSTEPS; s2 += 64) Wout[s2] = SLOT[s2].y * g;
  if (lane == 0) gOut[0] = g;
}

__global__ __launch_bounds__(64) void scan_real(const float* G, const float* u,
                                                const float* Kp, float* W,
                                                float* gS) {
  scan_body<0, 512>(G, u, Kp, W, gS);
}
__global__ __launch_bounds__(64) void scan_a0(const float* G, const float* u,
                                              const float* Kp, float* W,
                                              float* gS) {
  scan_body<0, 128>(G, u, Kp, W, gS);
}
__global__ __launch_bounds__(64) void scan_a1(const float* G, const float* u,
                                              const float* Kp, float* W,
                                              float* gS) {
  scan_body<1, 128>(G, u, Kp, W, gS);
}
__global__ __launch_bounds__(64) void scan_a2(const float* G, const float* u,
                                              const float* Kp, float* W,
                                              float* gS) {
  scan_body<2, 128>(G, u, Kp, W, gS);
}
__global__ __launch_bounds__(64) void scan_a3(const float* G, const float* u,
                                              const float* Kp, float* W,
                                              float* gS) {
  scan_body<3, 128>(G, u, Kp, W, gS);
}

extern "C" void kernel_launch(void* const* d_in, const int* in_sizes, int n_in,
                              void* d_out, int out_size, void* d_ws,
                              size_t ws_size, hipStream_t stream) {
  const float* E = (const float*)d_in[0];   // [512,384]
  const float* K0 = (const float*)d_in[1];  // [384,384]
  float* out = (float*)d_out;               // [512,384]

  float* G = (float*)d_ws;                  // 512*512
  float* M0 = G + 512 * 512;                // 512*384
  float* u = M0 + 512 * 384;                // 512
  float* W = u + 512;                       // 512
  float* gS = W + 512;                      // 1
  float* Kpart = gS + 1;                    // 64
  float* abl = Kpart + 64;                  // 4 x 513 throwaway

  gemm_nt<<<dim3(16, 16), 256, 0, stream>>>(E, E, G, 512, 384);     // G = E E^T
  gemm_nn<<<dim3(12, 16), 256, 0, stream>>>(E, K0, M0, 384, 384);   // M0 = E K0
  prep_kernel<<<192, 256, 0, stream>>>(E, M0, K0, u, Kpart);
  scan_real<<<1, 64, 0, stream>>>(G, u, Kpart, W, gS);
  scan_a0<<<1, 64, 0, stream>>>(G, u, Kpart, abl, abl + 512);
  scan_a1<<<1, 64, 0, stream>>>(G, u, Kpart, abl + 513, abl + 513 + 512);
  scan_a2<<<1, 64, 0, stream>>>(G, u, Kpart, abl + 1026, abl + 1026 + 512);
  scan_a3<<<1, 64, 0, stream>>>(G, u, Kpart, abl + 1539, abl + 1539 + 512);
  final_gemm<<<dim3(12, 16), 256, 0, stream>>>(G, E, M0, W, gS, out);
}

// Round 11
// 502.103 us; speedup vs baseline: 1.3117x; 1.3117x over previous
//
#include <hip/hip_runtime.h>

// ---------------------------------------------------------------------------
// SemanticMemoryLatentSpace, fully factored (see R7 header).
// R10: DECISIVE ATTRIBUTION. scan_real = [chain-only probe: 512 steps of the
// exact decision-chain op sequence, register-recycled, no LDS/global/lag]
// followed by the bit-identical R8 512-step loop (T_full ~= 346us known).
// Reported scan duration - 346us = T_chain. Ablation kernels removed (the
// harness top-5 only ever shows the slowest kernel's replays).
// ---------------------------------------------------------------------------

#define A_BOOSTF 0.012247448713915891f // 1.5*alpha (growth==0 always)

template <int CTRL>
__device__ __forceinline__ float dpp_f(float x) {
  return __int_as_float(
      __builtin_amdgcn_mov_dpp(__float_as_int(x), CTRL, 0xf, 0xf, true));
}
template <int CTRL>
__device__ __forceinline__ unsigned dpp_u(unsigned x) {
  return (unsigned)__builtin_amdgcn_mov_dpp((int)x, CTRL, 0xf, 0xf, true);
}
__device__ __forceinline__ float rdlane_f(float x, int l) {
  return __int_as_float(__builtin_amdgcn_readlane(__float_as_int(x), l));
}
__device__ __forceinline__ unsigned rdlane_u(unsigned x, int l) {
  return (unsigned)__builtin_amdgcn_readlane((int)x, l);
}
__device__ __forceinline__ float wave_sum64(float v) {
  v += dpp_f<0xB1>(v);
  v += dpp_f<0x4E>(v);
  v += dpp_f<0x124>(v);
  v += dpp_f<0x128>(v);
  return (rdlane_f(v, 0) + rdlane_f(v, 16)) + (rdlane_f(v, 32) + rdlane_f(v, 48));
}
__device__ __forceinline__ unsigned sortable(float v) {
  unsigned u = __float_as_uint(v);
  return u ^ (unsigned)(((int)u >> 31) | 0x80000000);
}
__device__ __forceinline__ float unsortable(unsigned x) {
  unsigned u = (x & 0x80000000u) ? (x ^ 0x80000000u) : ~x;
  return __uint_as_float(u);
}
__device__ __forceinline__ unsigned wave_umax64(unsigned v) {
  v = max(v, dpp_u<0xB1>(v));
  v = max(v, dpp_u<0x4E>(v));
  v = max(v, dpp_u<0x124>(v));
  v = max(v, dpp_u<0x128>(v));
  return max(max(rdlane_u(v, 0), rdlane_u(v, 16)),
             max(rdlane_u(v, 32), rdlane_u(v, 48)));
}

#define SELCOL(rowregs, cj, out)                                   \
  {                                                                \
    const int _g = (cj) >> 6, _l = (cj) & 63;                      \
    float _s = rowregs[0];                                         \
    _s = (_g == 1) ? rowregs[1] : _s;                              \
    _s = (_g == 2) ? rowregs[2] : _s;                              \
    _s = (_g == 3) ? rowregs[3] : _s;                              \
    out = rdlane_f(_s, _l);                                        \
  }

// ---------------- generic 32x32-tile fp32 GEMMs -----------------------------
__global__ __launch_bounds__(256) void gemm_nt(const float* __restrict__ A,
                                               const float* __restrict__ B,
                                               float* __restrict__ C,
                                               int N, int K) {
  __shared__ float As[32][33];
  __shared__ float Bs[32][33];
  int bx = blockIdx.x, by = blockIdx.y;
  int tid = threadIdx.x;
  int tx = tid & 15, ty = tid >> 4;
  float a00 = 0.f, a01 = 0.f, a10 = 0.f, a11 = 0.f;
  for (int k0 = 0; k0 < K; k0 += 32) {
    for (int l = tid; l < 1024; l += 256) {
      int r = l >> 5, c = l & 31;
      As[r][c] = A[(by * 32 + r) * K + k0 + c];
      Bs[r][c] = B[(bx * 32 + r) * K + k0 + c];
    }
    __syncthreads();
#pragma unroll
    for (int k = 0; k < 32; ++k) {
      float x0 = As[2 * ty][k], x1 = As[2 * ty + 1][k];
      float y0 = Bs[2 * tx][k], y1 = Bs[2 * tx + 1][k];
      a00 += x0 * y0; a01 += x0 * y1; a10 += x1 * y0; a11 += x1 * y1;
    }
    __syncthreads();
  }
  int i = by * 32 + 2 * ty, jj = bx * 32 + 2 * tx;
  C[i * N + jj] = a00;           C[i * N + jj + 1] = a01;
  C[(i + 1) * N + jj] = a10;     C[(i + 1) * N + jj + 1] = a11;
}

__global__ __launch_bounds__(256) void gemm_nn(const float* __restrict__ A,
                                               const float* __restrict__ B,
                                               float* __restrict__ C,
                                               int N, int K) {
  __shared__ float As[32][33];
  __shared__ float Bs[32][33];
  int bx = blockIdx.x, by = blockIdx.y;
  int tid = threadIdx.x;
  int tx = tid & 15, ty = tid >> 4;
  float a00 = 0.f, a01 = 0.f, a10 = 0.f, a11 = 0.f;
  for (int k0 = 0; k0 < K; k0 += 32) {
    for (int l = tid; l < 1024; l += 256) {
      int r = l >> 5, c = l & 31;
      As[r][c] = A[(by * 32 + r) * K + k0 + c];
      Bs[r][c] = B[(k0 + r) * N + bx * 32 + c];
    }
    __syncthreads();
#pragma unroll
    for (int k = 0; k < 32; ++k) {
      float x0 = As[2 * ty][k], x1 = As[2 * ty + 1][k];
      float y0 = Bs[k][2 * tx], y1 = Bs[k][2 * tx + 1];
      a00 += x0 * y0; a01 += x0 * y1; a10 += x1 * y0; a11 += x1 * y1;
    }
    __syncthreads();
  }
  int i = by * 32 + 2 * ty, jj = bx * 32 + 2 * tx;
  C[i * N + jj] = a00;           C[i * N + jj + 1] = a01;
  C[(i + 1) * N + jj] = a10;     C[(i + 1) * N + jj + 1] = a11;
}

__global__ __launch_bounds__(256) void final_gemm(const float* __restrict__ G,
                                                  const float* __restrict__ E,
                                                  const float* __restrict__ M0,
                                                  const float* __restrict__ W,
                                                  const float* __restrict__ gS,
                                                  float* __restrict__ out) {
  __shared__ float As[32][33];
  __shared__ float Bs[32][33];
  int bx = blockIdx.x, by = blockIdx.y;
  int tid = threadIdx.x;
  int tx = tid & 15, ty = tid >> 4;
  float a00 = 0.f, a01 = 0.f, a10 = 0.f, a11 = 0.f;
  for (int k0 = 0; k0 < 512; k0 += 32) {
    for (int l = tid; l < 1024; l += 256) {
      int r = l >> 5, c = l & 31;
      As[r][c] = G[(by * 32 + r) * 512 + k0 + c] * W[k0 + c];
      Bs[r][c] = E[(k0 + r) * 384 + bx * 32 + c];
    }
    __syncthreads();
#pragma unroll
    for (int k = 0; k < 32; ++k) {
      float x0 = As[2 * ty][k], x1 = As[2 * ty + 1][k];
      float y0 = Bs[k][2 * tx], y1 = Bs[k][2 * tx + 1];
      a00 += x0 * y0; a01 += x0 * y1; a10 += x1 * y0; a11 += x1 * y1;
    }
    __syncthreads();
  }
  float gv = gS[0];
  int i = by * 32 + 2 * ty, jj = bx * 32 + 2 * tx;
  out[i * 384 + jj]         = gv * M0[i * 384 + jj]         + a00;
  out[i * 384 + jj + 1]     = gv * M0[i * 384 + jj + 1]     + a01;
  out[(i + 1) * 384 + jj]     = gv * M0[(i + 1) * 384 + jj]     + a10;
  out[(i + 1) * 384 + jj + 1] = gv * M0[(i + 1) * 384 + jj + 1] + a11;
}

__global__ __launch_bounds__(256) void prep_kernel(const float* __restrict__ E,
                                                   const float* __restrict__ M0,
                                                   const float* __restrict__ K0,
                                                   float* __restrict__ u,
                                                   float* __restrict__ Kpart) {
  __shared__ double wr[4];
  int b = blockIdx.x;
  int tid = threadIdx.x, lane = tid & 63, wv = tid >> 6;
  if (b < 128) {
    int row = b * 4 + wv;
    const float4* e4 = (const float4*)(E + row * 384);
    const float4* m4 = (const float4*)(M0 + row * 384);
    float p = 0.f;
    for (int i = lane; i < 96; i += 64) {
      float4 a = e4[i], bb = m4[i];
      p += a.x * bb.x + a.y * bb.y + a.z * bb.z + a.w * bb.w;
    }
#pragma unroll
    for (int off = 32; off; off >>= 1) p += __shfl_down(p, off);
    if (lane == 0) u[row] = p;
  } else {
    int cb = b - 128;
    const float* p = K0 + cb * 2304 + tid * 9;
    double acc = 0.0;
#pragma unroll
    for (int i = 0; i < 9; ++i) { double v = (double)p[i]; acc += v * v; }
#pragma unroll
    for (int off = 32; off; off >>= 1) acc += __shfl_down(acc, off);
    if (lane == 0) wr[wv] = acc;
    __syncthreads();
    if (tid == 0) Kpart[cb] = (float)(wr[0] + wr[1] + wr[2] + wr[3]);
  }
}

// ---------------- single-wave scan: chain probe + real loop ----------------
__global__ __launch_bounds__(64) void scan_real(const float* __restrict__ G,
                                                const float* __restrict__ u,
                                                const float* __restrict__ Kpart,
                                                float* __restrict__ Wout,
                                                float* __restrict__ gOut) {
  __shared__ float RAW[128 * 257];
  __shared__ float4 SLOT[512];
  __shared__ float u_sh[512];

  const int lane = threadIdx.x;
  const int ro0 = lane * 257, ro1 = (lane + 64) * 257;

  // ============ CHAIN-ONLY PROBE: 512 steps, no LDS/global/lag =============
  // Replicates the real per-step decision-chain op sequence with register-
  // recycled data. scan_dur - 346us = this probe's duration.
  {
    float ps0 = 0.5f + (float)lane * 1e-3f, ps1 = 0.6f + (float)lane * 1e-3f;
    float pd0 = 1.f, pd1 = 1.f, pcn0 = 1.f, pcn1 = 2.f;
    float pr0[4], pr1[4];
#pragma unroll
    for (int k = 0; k < 4; ++k) {
      pr0[k] = 0.1f * (float)(lane + k);
      pr1[k] = 0.2f * (float)(lane + k);
    }
    int pnact = 100;
    for (int t = 0; t < 512; t += 4) {
      // per-round uniform scalars (mimics SELCOL tr/ren + gx readlanes)
      float tr[4], ren[4];
#pragma unroll
      for (int k = 0; k < 4; ++k) {
        tr[k] = rdlane_f(pr0[k], (t + k) & 63);
        ren[k] = __builtin_amdgcn_rcpf(
            __builtin_amdgcn_sqrtf(__builtin_fabsf(tr[k]) + 0.5f));
      }
      float gx01 = rdlane_f(pr1[0], (t + 1) & 63);
      float gx02 = rdlane_f(pr1[1], (t + 2) & 63);
      float gx03 = rdlane_f(pr1[2], (t + 3) & 63);
      float gx12 = rdlane_f(pr1[3], (t + 5) & 63);
      float gx13 = rdlane_f(pr0[1], (t + 6) & 63);
      float gx23 = rdlane_f(pr0[2], (t + 7) & 63);

#define PSTEP(K, PPATCH)                                                       \
      {                                                                        \
        float v0 = (lane < pnact) ? ps0 * ren[K] * pr0[K] : -2.f;              \
        float v1 = (lane + 64 < pnact) ? ps1 * ren[K] * pr1[K] : -2.f;         \
        unsigned pk0 = (sortable(v0) & ~127u) | (unsigned)(127 - lane);        \
        unsigned pk1 = (sortable(v1) & ~127u) | (unsigned)(63 - lane);         \
        unsigned P = wave_umax64(max(pk0, pk1));                               \
        int imax = 127 - (int)(P & 127u);                                      \
        float M = unsortable(P & ~127u);                                       \
        float nov = (pnact == 0) ? 1.f : fminf(1.f, fmaxf(0.f, 1.f - M * M));  \
        int create = (nov > 0.7f && pnact < 100) ? 1 : 0;                      \
        const int idxs = create ? pnact : imax;                                \
        const int cl = idxs & 63, hi = idxs >> 6;                              \
        float dcA = create ? 1.f : 0.95f * pd0;                                \
        float dcB = create ? 1.f : 0.95f * pd1;                                \
        float ccA = create ? tr[K]                                             \
                           : (0.9025f * pcn0 + 0.095f * (pd0 * pr0[K]) +       \
                              0.0025f * tr[K]);                                \
        float ccB = create ? tr[K]                                             \
                           : (0.9025f * pcn1 + 0.095f * (pd1 * pr1[K]) +       \
                              0.0025f * tr[K]);                                \
        float scA = dcA * __builtin_amdgcn_rcpf(__builtin_amdgcn_sqrtf(        \
                              __builtin_fabsf(ccA) + 1e-3f));                  \
        float scB = dcB * __builtin_amdgcn_rcpf(__builtin_amdgcn_sqrtf(        \
                              __builtin_fabsf(ccB) + 1e-3f));                  \
        bool own0 = (lane == cl) && (hi == 0);                                 \
        bool own1 = (lane == cl) && (hi == 1);                                 \
        pd0 = own0 ? dcA : pd0; pcn0 = own0 ? ccA : pcn0;                      \
        ps0 = own0 ? scA : ps0;                                                \
        pd1 = own1 ? dcB : pd1; pcn1 = own1 ? ccB : pcn1;                      \
        ps1 = own1 ? scB : ps1;                                                \
        float bnew = create ? 1.f                                              \
                            : 0.05f * __builtin_amdgcn_rcpf(                   \
                                          rdlane_f(hi ? dcB : dcA, cl));       \
        float pb0 = own0 ? bnew : 0.f, pb1 = own1 ? bnew : 0.f;                \
        PPATCH                                                                 \
        pr0[K] = __builtin_fmaf(pr0[K], 0.9999f, bnew * 1e-3f);                \
        pr1[K] = __builtin_fmaf(pr1[K], 0.9999f, bnew * 1e-3f);                \
      }

      PSTEP(0, { pr0[1] += pb0 * gx01; pr1[1] += pb1 * gx01;
                 pr0[2] += pb0 * gx02; pr1[2] += pb1 * gx02;
                 pr0[3] += pb0 * gx03; pr1[3] += pb1 * gx03; })
      PSTEP(1, { pr0[2] += pb0 * gx12; pr1[2] += pb1 * gx12;
                 pr0[3] += pb0 * gx13; pr1[3] += pb1 * gx13; })
      PSTEP(2, { pr0[3] += pb0 * gx23; pr1[3] += pb1 * gx23; })
      PSTEP(3, {})
#undef PSTEP

      // keep d in normal-float range (off-chain, 4 ops/round)
      pd0 = fmaxf(pd0, 0.25f); pd1 = fmaxf(pd1, 0.25f);
      pcn0 = fminf(fmaxf(pcn0, 1e-3f), 1e6f);
      pcn1 = fminf(fmaxf(pcn1, 1e-3f), 1e6f);
    }
    asm volatile("" ::"v"(ps0), "v"(ps1), "v"(pd0), "v"(pd1), "v"(pr0[0]),
                 "v"(pr0[1]), "v"(pr0[2]), "v"(pr0[3]), "v"(pr1[0]),
                 "v"(pr1[1]), "v"(pr1[2]), "v"(pr1[3]));
  }
  // ================== END PROBE — real loop (bit-identical R8) =============

  ((float4*)u_sh)[lane] = ((const float4*)u)[lane];
  ((float4*)u_sh)[lane + 64] = ((const float4*)u)[lane + 64];

  float d0 = 1.f, d1 = 1.f, cn0 = 0.f, cn1 = 0.f, s0 = 0.f, s1 = 0.f;
  float n2 = wave_sum64(Kpart[lane]);
  float g = 1.f, ginv = 1.f;
  float q[4] = {0.f, 0.f, 0.f, 0.f};
  int nact = 0;

  float4 z4 = {0.f, 0.f, 0.f, 0.f};
  for (int i = lane; i < 8224; i += 64) ((float4*)RAW)[i] = z4;

  float gr[4][4], pr[4][4];
#pragma unroll
  for (int k = 0; k < 4; ++k)
#pragma unroll
    for (int m = 0; m < 4; ++m) {
      gr[k][m] = G[k * 512 + m * 64 + lane];
      pr[k][m] = G[(4 + k) * 512 + m * 64 + lane];
    }
  float r0[4] = {0.f, 0.f, 0.f, 0.f}, r1[4] = {0.f, 0.f, 0.f, 0.f};

  for (int t = 0; t < 512; t += 4) {
    const int c = t & 255;
    if (t == 256) {
      for (int i = lane; i < 8224; i += 64) ((float4*)RAW)[i] = z4;
#pragma unroll
      for (int m = 0; m < 4; ++m) q[m] = 0.f;
      __builtin_amdgcn_sched_barrier(0);
      const float* Gb = G + 256;
      float A[4][4], Bv[4][4];
      float4 SA[4], SB[4];
#pragma unroll
      for (int j = 0; j < 4; ++j) {
#pragma unroll
        for (int m = 0; m < 4; ++m) A[j][m] = Gb[j * 512 + m * 64 + lane];
        SA[j] = SLOT[j];
      }
      for (int s = 0; s < 256; s += 8) {
#pragma unroll
        for (int j = 0; j < 4; ++j) {
#pragma unroll
          for (int m = 0; m < 4; ++m)
            Bv[j][m] = Gb[(s + 4 + j) * 512 + m * 64 + lane];
          SB[j] = SLOT[s + 4 + j];
        }
#pragma unroll
        for (int j = 0; j < 4; ++j) {
          float bh = SA[j].x, wh = SA[j].y;
          int id = __float_as_int(SA[j].z);
#pragma unroll
          for (int m = 0; m < 4; ++m) {
            atomicAdd(&RAW[id * 257 + m * 64 + lane], bh * A[j][m]);
            q[m] += wh * A[j][m] * A[j][m];
          }
        }
        if (s + 8 < 256) {
#pragma unroll
          for (int j = 0; j < 4; ++j) {
#pragma unroll
            for (int m = 0; m < 4; ++m)
              A[j][m] = Gb[(s + 8 + j) * 512 + m * 64 + lane];
            SA[j] = SLOT[s + 8 + j];
          }
        }
#pragma unroll
        for (int j = 0; j < 4; ++j) {
          float bh = SB[j].x, wh = SB[j].y;
          int id = __float_as_int(SB[j].z);
#pragma unroll
          for (int m = 0; m < 4; ++m) {
            atomicAdd(&RAW[id * 257 + m * 64 + lane], bh * Bv[j][m]);
            q[m] += wh * Bv[j][m] * Bv[j][m];
          }
        }
      }
      __builtin_amdgcn_sched_barrier(0);
#pragma unroll
      for (int k = 0; k < 4; ++k) { r0[k] = RAW[ro0 + k]; r1[k] = RAW[ro1 + k]; }
      __builtin_amdgcn_sched_barrier(0);
    }

    float prn[4][4];
    {
      const int tb = (t + 8 < 512) ? (t + 8) : 508;
      const int nb2 = tb & ~255;
#pragma unroll
      for (int k = 0; k < 4; ++k) {
        const int row = (t + 8 + k < 512) ? (t + 8 + k) : 511;
#pragma unroll
        for (int m = 0; m < 4; ++m)
          prn[k][m] = G[row * 512 + nb2 + m * 64 + lane];
      }
    }

    float4 uu = *(const float4*)&u_sh[t];

    float tr[4], ren[4], qc[4];
#pragma unroll
    for (int k = 0; k < 4; ++k) {
      SELCOL(gr[k], c + k, tr[k]);
      {
        const int _g = (c + k) >> 6, _l = (c + k) & 63;
        float _s = q[0];
        _s = (_g == 1) ? q[1] : _s;
        _s = (_g == 2) ? q[2] : _s;
        _s = (_g == 3) ? q[3] : _s;
        qc[k] = rdlane_f(_s, _l);
      }
      ren[k] = __builtin_amdgcn_rcpf(__builtin_amdgcn_sqrtf(tr[k]));
    }
    float gx01, gx02, gx03, gx12, gx13, gx23;
    SELCOL(gr[0], c + 1, gx01); SELCOL(gr[0], c + 2, gx02);
    SELCOL(gr[0], c + 3, gx03); SELCOL(gr[1], c + 2, gx12);
    SELCOL(gr[1], c + 3, gx13); SELCOL(gr[2], c + 3, gx23);

    float bnewA[4], novA[4];
    int idxA[4];

#define STEP(K, RPATCH)                                                        \
    {                                                                          \
      float v0 = (lane < nact) ? s0 * ren[K] * r0[K] : -2.f;                   \
      float v1 = (lane + 64 < nact) ? s1 * ren[K] * r1[K] : -2.f;              \
      unsigned pk0 = (sortable(v0) & ~127u) | (unsigned)(127 - lane);          \
      unsigned pk1 = (sortable(v1) & ~127u) | (unsigned)(63 - lane);           \
      unsigned P = wave_umax64(max(pk0, pk1));                                 \
      int imax = 127 - (int)(P & 127u);                                        \
      float M = unsortable(P & ~127u);                                         \
      float nov = (nact == 0) ? 1.f : fminf(1.f, fmaxf(0.f, 1.f - M * M));     \
      int create = (nov > 0.7f && nact < 100) ? 1 : 0;                         \
      const int idxs = create ? nact : imax;                                   \
      const int cl = idxs & 63, hi = idxs >> 6;                                \
      float dcA = create ? 1.f : 0.95f * d0;                                   \
      float dcB = create ? 1.f : 0.95f * d1;                                   \
      float ccA = create ? tr[K]                                               \
                         : (0.9025f * cn0 + 0.095f * (d0 * r0[K]) + 0.0025f * tr[K]); \
      float ccB = create ? tr[K]                                               \
                         : (0.9025f * cn1 + 0.095f * (d1 * r1[K]) + 0.0025f * tr[K]); \
      float scA = dcA * __builtin_amdgcn_rcpf(__builtin_amdgcn_sqrtf(ccA));    \
      float scB = dcB * __builtin_amdgcn_rcpf(__builtin_amdgcn_sqrtf(ccB));    \
      bool own0 = (lane == cl) && (hi == 0);                                   \
      bool own1 = (lane == cl) && (hi == 1);                                   \
      d0 = own0 ? dcA : d0; cn0 = own0 ? ccA : cn0; s0 = own0 ? scA : s0;      \
      d1 = own1 ? dcB : d1; cn1 = own1 ? ccB : cn1; s1 = own1 ? scB : s1;      \
      float bnew = create ? 1.f                                                \
                          : 0.05f * __builtin_amdgcn_rcpf(                     \
                                        rdlane_f(hi ? dcB : dcA, cl));         \
      nact += create;                                                          \
      float pb0 = own0 ? bnew : 0.f, pb1 = own1 ? bnew : 0.f;                  \
      RPATCH                                                                   \
      bnewA[K] = bnew; novA[K] = nov; idxA[K] = idxs;                          \
      _Pragma("unroll")                                                        \
      for (int m = 0; m < 4; ++m)                                              \
        if (m * 64 + 63 >= c)                                                  \
          atomicAdd(&RAW[idxs * 257 + m * 64 + lane], bnew * gr[K][m]);        \
    }

    STEP(0, { r0[1] += pb0 * gx01; r1[1] += pb1 * gx01;
              r0[2] += pb0 * gx02; r1[2] += pb1 * gx02;
              r0[3] += pb0 * gx03; r1[3] += pb1 * gx03; })
    STEP(1, { r0[2] += pb0 * gx12; r1[2] += pb1 * gx12;
              r0[3] += pb0 * gx13; r1[3] += pb1 * gx13; })
    STEP(2, { r0[3] += pb0 * gx23; r1[3] += pb1 * gx23; })
    STEP(3, {})
#undef STEP

    if (((t + 4) & 255) != 0) {
      const int c4 = c + 4;
#pragma unroll
      for (int k = 0; k < 4; ++k) {
        r0[k] = RAW[ro0 + c4 + k];
        r1[k] = RAW[ro1 + c4 + k];
      }
    }
    __builtin_amdgcn_sched_barrier(0);

    float whA[4];
    {
      float um[4] = {uu.x, uu.y, uu.z, uu.w};
      float qeff1 = qc[1], qeff2 = qc[2], qeff3 = qc[3];
#pragma unroll
      for (int m = 0; m < 4; ++m) {
        float qe = (m == 0) ? qc[0] : ((m == 1) ? qeff1 : ((m == 2) ? qeff2 : qeff3));
        float iw = novA[m] * __builtin_amdgcn_sqrtf(novA[m]);
        float psc = 384.0f * __builtin_amdgcn_rcpf(fmaxf(tr[m], 1e-8f));
        float ccf = A_BOOSTF * iw * psc;
        float qv = g * (um[m] + qe);
        float n2n = n2 + 2.f * ccf * qv + ccf * ccf * tr[m] * tr[m];
        float kn = __builtin_amdgcn_sqrtf(n2n);
        float fct = (kn > 50.f) ? 50.f * __builtin_amdgcn_rcpf(kn) : 1.f;
        float fiv = (kn > 50.f) ? kn * 0.02f : 1.f;
        whA[m] = ccf * ginv;
        n2 = n2n * fct * fct; g *= fct; ginv *= fiv;
        if (m == 0) {
          qeff1 += whA[0] * gx01 * gx01;
          qeff2 += whA[0] * gx02 * gx02;
          qeff3 += whA[0] * gx03 * gx03;
        } else if (m == 1) {
          qeff2 += whA[1] * gx12 * gx12;
          qeff3 += whA[1] * gx13 * gx13;
        } else if (m == 2) {
          qeff3 += whA[2] * gx23 * gx23;
        }
      }
#pragma unroll
      for (int m = 0; m < 4; ++m)
#pragma unroll
        for (int k = 0; k < 4; ++k) q[m] += whA[k] * gr[k][m] * gr[k][m];
    }

    if (lane == 0) {
#pragma unroll
      for (int k = 0; k < 4; ++k) {
        float4 rec = {bnewA[k], whA[k], __int_as_float(idxA[k]), 0.f};
        SLOT[t + k] = rec;
      }
    }

#pragma unroll
    for (int k = 0; k < 4; ++k)
#pragma unroll
      for (int m = 0; m < 4; ++m) { gr[k][m] = pr[k][m]; pr[k][m] = prn[k][m]; }
  }

  for (int s2 = lane; s2 < 512; s2 += 64) Wout[s2] = SLOT[s2].y * g;
  if (lane == 0) gOut[0] = g;
}

extern "C" void kernel_launch(void* const* d_in, const int* in_sizes, int n_in,
                              void* d_out, int out_size, void* d_ws,
                              size_t ws_size, hipStream_t stream) {
  const float* E = (const float*)d_in[0];   // [512,384]
  const float* K0 = (const float*)d_in[1];  // [384,384]
  float* out = (float*)d_out;               // [512,384]

  float* G = (float*)d_ws;                  // 512*512
  float* M0 = G + 512 * 512;                // 512*384
  float* u = M0 + 512 * 384;                // 512
  float* W = u + 512;                       // 512
  float* gS = W + 512;                      // 1
  float* Kpart = gS + 1;                    // 64

  gemm_nt<<<dim3(16, 16), 256, 0, stream>>>(E, E, G, 512, 384);     // G = E E^T
  gemm_nn<<<dim3(12, 16), 256, 0, stream>>>(E, K0, M0, 384, 384);   // M0 = E K0
  prep_kernel<<<192, 256, 0, stream>>>(E, M0, K0, u, Kpart);
  scan_real<<<1, 64, 0, stream>>>(G, u, Kpart, W, gS);
  final_gemm<<<dim3(12, 16), 256, 0, stream>>>(G, E, M0, W, gS, out);
}

// Round 12
// 430.017 us; speedup vs baseline: 1.5316x; 1.1676x over previous
//
#include <hip/hip_runtime.h>

// ---------------------------------------------------------------------------
// SemanticMemoryLatentSpace, fully factored (see R7 header).
// R11: producer/consumer wave split (single-wave in-order issue was the
// bottleneck: chain=87us of 346us; rest=DS/lag/prefetch/SLOT in-order issue).
//   wave 0: decision chain only (no global access; tr/ren/gx from LDS TRGX).
//   wave 1: RAW atomics (1 phase behind), q, n2/g lag, SLOT, G prefetch,
//           TRGX extraction, t=256 rebuild.
// Identical arithmetic to R8 -> bitwise-same output.
// ---------------------------------------------------------------------------

#define A_BOOSTF 0.012247448713915891f // 1.5*alpha (growth==0 always)

template <int CTRL>
__device__ __forceinline__ float dpp_f(float x) {
  return __int_as_float(
      __builtin_amdgcn_mov_dpp(__float_as_int(x), CTRL, 0xf, 0xf, true));
}
template <int CTRL>
__device__ __forceinline__ unsigned dpp_u(unsigned x) {
  return (unsigned)__builtin_amdgcn_mov_dpp((int)x, CTRL, 0xf, 0xf, true);
}
__device__ __forceinline__ float rdlane_f(float x, int l) {
  return __int_as_float(__builtin_amdgcn_readlane(__float_as_int(x), l));
}
__device__ __forceinline__ unsigned rdlane_u(unsigned x, int l) {
  return (unsigned)__builtin_amdgcn_readlane((int)x, l);
}
__device__ __forceinline__ float wave_sum64(float v) {
  v += dpp_f<0xB1>(v);
  v += dpp_f<0x4E>(v);
  v += dpp_f<0x124>(v);
  v += dpp_f<0x128>(v);
  return (rdlane_f(v, 0) + rdlane_f(v, 16)) + (rdlane_f(v, 32) + rdlane_f(v, 48));
}
__device__ __forceinline__ unsigned sortable(float v) {
  unsigned u = __float_as_uint(v);
  return u ^ (unsigned)(((int)u >> 31) | 0x80000000);
}
__device__ __forceinline__ float unsortable(unsigned x) {
  unsigned u = (x & 0x80000000u) ? (x ^ 0x80000000u) : ~x;
  return __uint_as_float(u);
}
__device__ __forceinline__ unsigned wave_umax64(unsigned v) {
  v = max(v, dpp_u<0xB1>(v));
  v = max(v, dpp_u<0x4E>(v));
  v = max(v, dpp_u<0x124>(v));
  v = max(v, dpp_u<0x128>(v));
  return max(max(rdlane_u(v, 0), rdlane_u(v, 16)),
             max(rdlane_u(v, 32), rdlane_u(v, 48)));
}

#define SELCOL(rowregs, cj, out)                                   \
  {                                                                \
    const int _g = (cj) >> 6, _l = (cj) & 63;                      \
    float _s = rowregs[0];                                         \
    _s = (_g == 1) ? rowregs[1] : _s;                              \
    _s = (_g == 2) ? rowregs[2] : _s;                              \
    _s = (_g == 3) ? rowregs[3] : _s;                              \
    out = rdlane_f(_s, _l);                                        \
  }

// ---------------- generic 32x32-tile fp32 GEMMs -----------------------------
__global__ __launch_bounds__(256) void gemm_nt(const float* __restrict__ A,
                                               const float* __restrict__ B,
                                               float* __restrict__ C,
                                               int N, int K) {
  __shared__ float As[32][33];
  __shared__ float Bs[32][33];
  int bx = blockIdx.x, by = blockIdx.y;
  int tid = threadIdx.x;
  int tx = tid & 15, ty = tid >> 4;
  float a00 = 0.f, a01 = 0.f, a10 = 0.f, a11 = 0.f;
  for (int k0 = 0; k0 < K; k0 += 32) {
    for (int l = tid; l < 1024; l += 256) {
      int r = l >> 5, c = l & 31;
      As[r][c] = A[(by * 32 + r) * K + k0 + c];
      Bs[r][c] = B[(bx * 32 + r) * K + k0 + c];
    }
    __syncthreads();
#pragma unroll
    for (int k = 0; k < 32; ++k) {
      float x0 = As[2 * ty][k], x1 = As[2 * ty + 1][k];
      float y0 = Bs[2 * tx][k], y1 = Bs[2 * tx + 1][k];
      a00 += x0 * y0; a01 += x0 * y1; a10 += x1 * y0; a11 += x1 * y1;
    }
    __syncthreads();
  }
  int i = by * 32 + 2 * ty, jj = bx * 32 + 2 * tx;
  C[i * N + jj] = a00;           C[i * N + jj + 1] = a01;
  C[(i + 1) * N + jj] = a10;     C[(i + 1) * N + jj + 1] = a11;
}

__global__ __launch_bounds__(256) void gemm_nn(const float* __restrict__ A,
                                               const float* __restrict__ B,
                                               float* __restrict__ C,
                                               int N, int K) {
  __shared__ float As[32][33];
  __shared__ float Bs[32][33];
  int bx = blockIdx.x, by = blockIdx.y;
  int tid = threadIdx.x;
  int tx = tid & 15, ty = tid >> 4;
  float a00 = 0.f, a01 = 0.f, a10 = 0.f, a11 = 0.f;
  for (int k0 = 0; k0 < K; k0 += 32) {
    for (int l = tid; l < 1024; l += 256) {
      int r = l >> 5, c = l & 31;
      As[r][c] = A[(by * 32 + r) * K + k0 + c];
      Bs[r][c] = B[(k0 + r) * N + bx * 32 + c];
    }
    __syncthreads();
#pragma unroll
    for (int k = 0; k < 32; ++k) {
      float x0 = As[2 * ty][k], x1 = As[2 * ty + 1][k];
      float y0 = Bs[k][2 * tx], y1 = Bs[k][2 * tx + 1];
      a00 += x0 * y0; a01 += x0 * y1; a10 += x1 * y0; a11 += x1 * y1;
    }
    __syncthreads();
  }
  int i = by * 32 + 2 * ty, jj = bx * 32 + 2 * tx;
  C[i * N + jj] = a00;           C[i * N + jj + 1] = a01;
  C[(i + 1) * N + jj] = a10;     C[(i + 1) * N + jj + 1] = a11;
}

__global__ __launch_bounds__(256) void final_gemm(const float* __restrict__ G,
                                                  const float* __restrict__ E,
                                                  const float* __restrict__ M0,
                                                  const float* __restrict__ W,
                                                  const float* __restrict__ gS,
                                                  float* __restrict__ out) {
  __shared__ float As[32][33];
  __shared__ float Bs[32][33];
  int bx = blockIdx.x, by = blockIdx.y;
  int tid = threadIdx.x;
  int tx = tid & 15, ty = tid >> 4;
  float a00 = 0.f, a01 = 0.f, a10 = 0.f, a11 = 0.f;
  for (int k0 = 0; k0 < 512; k0 += 32) {
    for (int l = tid; l < 1024; l += 256) {
      int r = l >> 5, c = l & 31;
      As[r][c] = G[(by * 32 + r) * 512 + k0 + c] * W[k0 + c];
      Bs[r][c] = E[(k0 + r) * 384 + bx * 32 + c];
    }
    __syncthreads();
#pragma unroll
    for (int k = 0; k < 32; ++k) {
      float x0 = As[2 * ty][k], x1 = As[2 * ty + 1][k];
      float y0 = Bs[k][2 * tx], y1 = Bs[k][2 * tx + 1];
      a00 += x0 * y0; a01 += x0 * y1; a10 += x1 * y0; a11 += x1 * y1;
    }
    __syncthreads();
  }
  float gv = gS[0];
  int i = by * 32 + 2 * ty, jj = bx * 32 + 2 * tx;
  out[i * 384 + jj]         = gv * M0[i * 384 + jj]         + a00;
  out[i * 384 + jj + 1]     = gv * M0[i * 384 + jj + 1]     + a01;
  out[(i + 1) * 384 + jj]     = gv * M0[(i + 1) * 384 + jj]     + a10;
  out[(i + 1) * 384 + jj + 1] = gv * M0[(i + 1) * 384 + jj + 1] + a11;
}

__global__ __launch_bounds__(256) void prep_kernel(const float* __restrict__ E,
                                                   const float* __restrict__ M0,
                                                   const float* __restrict__ K0,
                                                   float* __restrict__ u,
                                                   float* __restrict__ Kpart) {
  __shared__ double wr[4];
  int b = blockIdx.x;
  int tid = threadIdx.x, lane = tid & 63, wv = tid >> 6;
  if (b < 128) {
    int row = b * 4 + wv;
    const float4* e4 = (const float4*)(E + row * 384);
    const float4* m4 = (const float4*)(M0 + row * 384);
    float p = 0.f;
    for (int i = lane; i < 96; i += 64) {
      float4 a = e4[i], bb = m4[i];
      p += a.x * bb.x + a.y * bb.y + a.z * bb.z + a.w * bb.w;
    }
#pragma unroll
    for (int off = 32; off; off >>= 1) p += __shfl_down(p, off);
    if (lane == 0) u[row] = p;
  } else {
    int cb = b - 128;
    const float* p = K0 + cb * 2304 + tid * 9;
    double acc = 0.0;
#pragma unroll
    for (int i = 0; i < 9; ++i) { double v = (double)p[i]; acc += v * v; }
#pragma unroll
    for (int off = 32; off; off >>= 1) acc += __shfl_down(acc, off);
    if (lane == 0) wr[wv] = acc;
    __syncthreads();
    if (tid == 0) Kpart[cb] = (float)(wr[0] + wr[1] + wr[2] + wr[3]);
  }
}

// ---------------- two-wave producer/consumer scan ---------------------------
__global__ __launch_bounds__(128) void scan_kernel(const float* __restrict__ G,
                                                   const float* __restrict__ u,
                                                   const float* __restrict__ Kpart,
                                                   float* __restrict__ Wout,
                                                   float* __restrict__ gOut) {
  __shared__ float RAW[128 * 257];   // [cluster][col], 257 -> 2-way col reads
  __shared__ float4 SLOT[512];       // journal {bhat, what, idx, 0}
  __shared__ float u_sh[512];
  __shared__ float4 MB[4];           // mailbox: {bnew, idx(bits), nov, tr}
  __shared__ float TRGX[2][16];      // per-round scalars {tr[4],ren[4],gx[6]}

  const int tid = threadIdx.x;
  const int wid = tid >> 6;          // 0 = decision wave, 1 = memory wave
  const int lane = tid & 63;
  const int ro0 = lane * 257, ro1 = (lane + 64) * 257;

  // wave-0 state
  float d0 = 1.f, d1 = 1.f, cn0 = 0.f, cn1 = 0.f, s0 = 0.f, s1 = 0.f;
  int nact = 0;
  float r0[4] = {0.f, 0.f, 0.f, 0.f}, r1[4] = {0.f, 0.f, 0.f, 0.f};

  // wave-1 state
  float n2 = 0.f, g = 1.f, ginv = 1.f;
  float q[4] = {0.f, 0.f, 0.f, 0.f};
  float gr[4][4], pr[4][4], prn[4][4], grPrev[4][4];
  float4 mbp[4];

  // ---- init ----
  float4 z4 = {0.f, 0.f, 0.f, 0.f};
  for (int i = tid; i < 8224; i += 128) ((float4*)RAW)[i] = z4;

#define EXTRACT(ROWS, RN)                                                      \
  {                                                                            \
    const int c1_ = (4 * (RN)) & 255;                                          \
    float et0, et1, et2, et3, eg0, eg1, eg2, eg3, eg4, eg5;                    \
    SELCOL(ROWS[0], c1_ + 0, et0); SELCOL(ROWS[1], c1_ + 1, et1);              \
    SELCOL(ROWS[2], c1_ + 2, et2); SELCOL(ROWS[3], c1_ + 3, et3);              \
    SELCOL(ROWS[0], c1_ + 1, eg0); SELCOL(ROWS[0], c1_ + 2, eg1);              \
    SELCOL(ROWS[0], c1_ + 3, eg2); SELCOL(ROWS[1], c1_ + 2, eg3);              \
    SELCOL(ROWS[1], c1_ + 3, eg4); SELCOL(ROWS[2], c1_ + 3, eg5);              \
    float er0 = __builtin_amdgcn_rcpf(__builtin_amdgcn_sqrtf(et0));            \
    float er1 = __builtin_amdgcn_rcpf(__builtin_amdgcn_sqrtf(et1));            \
    float er2 = __builtin_amdgcn_rcpf(__builtin_amdgcn_sqrtf(et2));            \
    float er3 = __builtin_amdgcn_rcpf(__builtin_amdgcn_sqrtf(et3));            \
    if (lane == 0) {                                                           \
      float* tb_ = TRGX[(RN) & 1];                                             \
      tb_[0] = et0;  tb_[1] = et1;  tb_[2] = et2;  tb_[3] = et3;               \
      tb_[4] = er0;  tb_[5] = er1;  tb_[6] = er2;  tb_[7] = er3;               \
      tb_[8] = eg0;  tb_[9] = eg1;  tb_[10] = eg2; tb_[11] = eg3;              \
      tb_[12] = eg4; tb_[13] = eg5;                                            \
    }                                                                          \
  }

  if (wid == 1) {
    ((float4*)u_sh)[lane] = ((const float4*)u)[lane];
    ((float4*)u_sh)[lane + 64] = ((const float4*)u)[lane + 64];
    n2 = wave_sum64(Kpart[lane]);
#pragma unroll
    for (int k = 0; k < 4; ++k)
#pragma unroll
      for (int m = 0; m < 4; ++m) {
        gr[k][m] = G[k * 512 + m * 64 + lane];
        pr[k][m] = G[(4 + k) * 512 + m * 64 + lane];
      }
    EXTRACT(gr, 0);
  }
  __syncthreads();

#define W0STEP(K, RPATCH)                                                      \
  {                                                                            \
    float v0 = (lane < nact) ? s0 * renk[K] * r0[K] : -2.f;                    \
    float v1 = (lane + 64 < nact) ? s1 * renk[K] * r1[K] : -2.f;               \
    unsigned pk0 = (sortable(v0) & ~127u) | (unsigned)(127 - lane);            \
    unsigned pk1 = (sortable(v1) & ~127u) | (unsigned)(63 - lane);             \
    unsigned P = wave_umax64(max(pk0, pk1));                                   \
    int imax = 127 - (int)(P & 127u);                                          \
    float M = unsortable(P & ~127u);                                           \
    float nov = (nact == 0) ? 1.f : fminf(1.f, fmaxf(0.f, 1.f - M * M));       \
    int create = (nov > 0.7f && nact < 100) ? 1 : 0;                           \
    const int idxs = create ? nact : imax;                                     \
    const int cl = idxs & 63, hi = idxs >> 6;                                  \
    float dcA = create ? 1.f : 0.95f * d0;                                     \
    float dcB = create ? 1.f : 0.95f * d1;                                     \
    float ccA = create ? trk[K]                                                \
                       : (0.9025f * cn0 + 0.095f * (d0 * r0[K]) + 0.0025f * trk[K]); \
    float ccB = create ? trk[K]                                                \
                       : (0.9025f * cn1 + 0.095f * (d1 * r1[K]) + 0.0025f * trk[K]); \
    float scA = dcA * __builtin_amdgcn_rcpf(__builtin_amdgcn_sqrtf(ccA));      \
    float scB = dcB * __builtin_amdgcn_rcpf(__builtin_amdgcn_sqrtf(ccB));      \
    bool own0 = (lane == cl) && (hi == 0);                                     \
    bool own1 = (lane == cl) && (hi == 1);                                     \
    d0 = own0 ? dcA : d0; cn0 = own0 ? ccA : cn0; s0 = own0 ? scA : s0;        \
    d1 = own1 ? dcB : d1; cn1 = own1 ? ccB : cn1; s1 = own1 ? scB : s1;        \
    float bnew = create ? 1.f                                                  \
                        : 0.05f * __builtin_amdgcn_rcpf(                       \
                                      rdlane_f(hi ? dcB : dcA, cl));           \
    nact += create;                                                            \
    float pb0 = own0 ? bnew : 0.f, pb1 = own1 ? bnew : 0.f;                    \
    RPATCH                                                                     \
    mbs[K].x = bnew; mbs[K].y = __int_as_float(idxs);                          \
    mbs[K].z = nov;  mbs[K].w = trk[K];                                        \
  }

#define WAVE0_ROUND()                                                          \
  {                                                                            \
    const float* tb_ = TRGX[par];                                              \
    float4 tA = ((const float4*)tb_)[0];                                       \
    float4 tB = ((const float4*)tb_)[1];                                       \
    float4 tC = ((const float4*)tb_)[2];                                       \
    float4 tD = ((const float4*)tb_)[3];                                       \
    float trk[4] = {tA.x, tA.y, tA.z, tA.w};                                   \
    float renk[4] = {tB.x, tB.y, tB.z, tB.w};                                  \
    float gx01 = tC.x, gx02 = tC.y, gx03 = tC.z, gx12 = tC.w;                  \
    float gx13 = tD.x, gx23 = tD.y;                                            \
    r0[0] = RAW[ro0 + c];     r1[0] = RAW[ro1 + c];                            \
    r0[1] = RAW[ro0 + c + 1]; r1[1] = RAW[ro1 + c + 1];                        \
    r0[2] = RAW[ro0 + c + 2]; r1[2] = RAW[ro1 + c + 2];                        \
    r0[3] = RAW[ro0 + c + 3]; r1[3] = RAW[ro1 + c + 3];                        \
    float4 mbs[4];                                                             \
    W0STEP(0, { r0[1] += pb0 * gx01; r1[1] += pb1 * gx01;                      \
                r0[2] += pb0 * gx02; r1[2] += pb1 * gx02;                      \
                r0[3] += pb0 * gx03; r1[3] += pb1 * gx03; })                   \
    W0STEP(1, { r0[2] += pb0 * gx12; r1[2] += pb1 * gx12;                      \
                r0[3] += pb0 * gx13; r1[3] += pb1 * gx13; })                   \
    W0STEP(2, { r0[3] += pb0 * gx23; r1[3] += pb1 * gx23; })                   \
    W0STEP(3, {})                                                              \
    if (lane == 0) { MB[0] = mbs[0]; MB[1] = mbs[1];                           \
                     MB[2] = mbs[2]; MB[3] = mbs[3]; }                         \
  }

#define POSTWORK(P)                                                            \
  {                                                                            \
    const int tp_ = 4 * (P), cp_ = tp_ & 255;                                  \
    const float* tb_ = TRGX[(P) & 1];                                          \
    float gxp01 = tb_[8],  gxp02 = tb_[9],  gxp03 = tb_[10];                   \
    float gxp12 = tb_[11], gxp13 = tb_[12], gxp23 = tb_[13];                   \
    float4 uu = *(const float4*)&u_sh[tp_];                                    \
    float um[4] = {uu.x, uu.y, uu.z, uu.w};                                    \
    float qcp[4];                                                              \
    _Pragma("unroll")                                                          \
    for (int k = 0; k < 4; ++k) {                                              \
      const int _g = (cp_ + k) >> 6, _l = (cp_ + k) & 63;                      \
      float _s = q[0];                                                         \
      _s = (_g == 1) ? q[1] : _s;                                              \
      _s = (_g == 2) ? q[2] : _s;                                              \
      _s = (_g == 3) ? q[3] : _s;                                              \
      qcp[k] = rdlane_f(_s, _l);                                               \
    }                                                                          \
    float wh[4];                                                               \
    float qeff1 = qcp[1], qeff2 = qcp[2], qeff3 = qcp[3];                      \
    _Pragma("unroll")                                                          \
    for (int m = 0; m < 4; ++m) {                                              \
      float nov = mbp[m].z, trm = mbp[m].w;                                    \
      float qe = (m == 0) ? qcp[0]                                             \
                          : ((m == 1) ? qeff1 : ((m == 2) ? qeff2 : qeff3));   \
      float iw = nov * __builtin_amdgcn_sqrtf(nov);                            \
      float psc = 384.0f * __builtin_amdgcn_rcpf(fmaxf(trm, 1e-8f));           \
      float ccf = A_BOOSTF * iw * psc;                                         \
      float qv = g * (um[m] + qe);                                             \
      float n2n = n2 + 2.f * ccf * qv + ccf * ccf * trm * trm;                 \
      float kn = __builtin_amdgcn_sqrtf(n2n);                                  \
      float fct = (kn > 50.f) ? 50.f * __builtin_amdgcn_rcpf(kn) : 1.f;        \
      float fiv = (kn > 50.f) ? kn * 0.02f : 1.f;                              \
      wh[m] = ccf * ginv;                                                      \
      n2 = n2n * fct * fct; g *= fct; ginv *= fiv;                             \
      if (m == 0) {                                                            \
        qeff1 += wh[0] * gxp01 * gxp01;                                        \
        qeff2 += wh[0] * gxp02 * gxp02;                                        \
        qeff3 += wh[0] * gxp03 * gxp03;                                        \
      } else if (m == 1) {                                                     \
        qeff2 += wh[1] * gxp12 * gxp12;                                        \
        qeff3 += wh[1] * gxp13 * gxp13;                                        \
      } else if (m == 2) {                                                     \
        qeff3 += wh[2] * gxp23 * gxp23;                                        \
      }                                                                        \
    }                                                                          \
    _Pragma("unroll")                                                          \
    for (int m = 0; m < 4; ++m)                                                \
      _Pragma("unroll")                                                        \
      for (int k = 0; k < 4; ++k)                                              \
        q[m] += wh[k] * grPrev[k][m] * grPrev[k][m];                           \
    if (lane == 0) {                                                           \
      _Pragma("unroll")                                                        \
      for (int k = 0; k < 4; ++k) {                                            \
        float4 rec;                                                            \
        rec.x = mbp[k].x; rec.y = wh[k]; rec.z = mbp[k].y; rec.w = 0.f;        \
        SLOT[tp_ + k] = rec;                                                   \
      }                                                                        \
    }                                                                          \
  }

  // ---- main loop ----
  for (int R = 0; R < 128; ++R) {
    const int t = 4 * R;
    const int c = t & 255;
    const int par = R & 1;
    const bool special = (t == 256);

    // ---------------- phase 1 ----------------
    if (wid == 1) {
      if (R > 0) POSTWORK(R - 1);
      EXTRACT(pr, R + 1);
      {
        const int tb = (t + 8 < 512) ? (t + 8) : 508;
        const int nb2 = tb & ~255;
#pragma unroll
        for (int k = 0; k < 4; ++k) {
          const int row = (t + 8 + k < 512) ? (t + 8 + k) : 511;
#pragma unroll
          for (int m = 0; m < 4; ++m)
            prn[k][m] = G[row * 512 + nb2 + m * 64 + lane];
        }
      }
    } else if (!special) {
      WAVE0_ROUND();
    }
    __syncthreads();

    if (special) {
      // rebuild for cols [256,512): zero (both waves), replay (wave 1)
      for (int i = tid; i < 8224; i += 128) ((float4*)RAW)[i] = z4;
      if (wid == 1) { q[0] = 0.f; q[1] = 0.f; q[2] = 0.f; q[3] = 0.f; }
      __syncthreads();
      if (wid == 1) {
        const float* Gb = G + 256;
        float A[4][4], Bv[4][4];
        float4 SA[4], SB[4];
#pragma unroll
        for (int j = 0; j < 4; ++j) {
#pragma unroll
          for (int m = 0; m < 4; ++m) A[j][m] = Gb[j * 512 + m * 64 + lane];
          SA[j] = SLOT[j];
        }
        for (int s = 0; s < 256; s += 8) {
#pragma unroll
          for (int j = 0; j < 4; ++j) {
#pragma unroll
            for (int m = 0; m < 4; ++m)
              Bv[j][m] = Gb[(s + 4 + j) * 512 + m * 64 + lane];
            SB[j] = SLOT[s + 4 + j];
          }
#pragma unroll
          for (int j = 0; j < 4; ++j) {
            float bh = SA[j].x, wh_ = SA[j].y;
            int id = __float_as_int(SA[j].z);
#pragma unroll
            for (int m = 0; m < 4; ++m) {
              atomicAdd(&RAW[id * 257 + m * 64 + lane], bh * A[j][m]);
              q[m] += wh_ * A[j][m] * A[j][m];
            }
          }
          if (s + 8 < 256) {
#pragma unroll
            for (int j = 0; j < 4; ++j) {
#pragma unroll
              for (int m = 0; m < 4; ++m)
                A[j][m] = Gb[(s + 8 + j) * 512 + m * 64 + lane];
              SA[j] = SLOT[s + 8 + j];
            }
          }
#pragma unroll
          for (int j = 0; j < 4; ++j) {
            float bh = SB[j].x, wh_ = SB[j].y;
            int id = __float_as_int(SB[j].z);
#pragma unroll
            for (int m = 0; m < 4; ++m) {
              atomicAdd(&RAW[id * 257 + m * 64 + lane], bh * Bv[j][m]);
              q[m] += wh_ * Bv[j][m] * Bv[j][m];
            }
          }
        }
        asm volatile("s_waitcnt lgkmcnt(0)");
      }
      __syncthreads();
      if (wid == 0) WAVE0_ROUND();
      __syncthreads();
    }

    // ---------------- phase 2 ----------------
    if (wid == 1) {
      float4 m0_ = MB[0], m1_ = MB[1], m2_ = MB[2], m3_ = MB[3];
      {
        int id0 = __float_as_int(m0_.y), id1 = __float_as_int(m1_.y);
        int id2 = __float_as_int(m2_.y), id3 = __float_as_int(m3_.y);
#pragma unroll
        for (int m = 0; m < 4; ++m) {
          if (m * 64 + 63 >= c) {
            atomicAdd(&RAW[id0 * 257 + m * 64 + lane], m0_.x * gr[0][m]);
            atomicAdd(&RAW[id1 * 257 + m * 64 + lane], m1_.x * gr[1][m]);
            atomicAdd(&RAW[id2 * 257 + m * 64 + lane], m2_.x * gr[2][m]);
            atomicAdd(&RAW[id3 * 257 + m * 64 + lane], m3_.x * gr[3][m]);
          }
        }
      }
      asm volatile("s_waitcnt lgkmcnt(0)");
      mbp[0] = m0_; mbp[1] = m1_; mbp[2] = m2_; mbp[3] = m3_;
#pragma unroll
      for (int k = 0; k < 4; ++k)
#pragma unroll
        for (int m = 0; m < 4; ++m) {
          grPrev[k][m] = gr[k][m];
          gr[k][m] = pr[k][m];
          pr[k][m] = prn[k][m];
        }
    }
    __syncthreads();
  }

  // ---- epilogue: finish round 127's postwork, write outputs ----
  if (wid == 1) {
    POSTWORK(127);
    for (int s2 = lane; s2 < 512; s2 += 64) Wout[s2] = SLOT[s2].y * g;
    if (lane == 0) gOut[0] = g;
  }
}

extern "C" void kernel_launch(void* const* d_in, const int* in_sizes, int n_in,
                              void* d_out, int out_size, void* d_ws,
                              size_t ws_size, hipStream_t stream) {
  const float* E = (const float*)d_in[0];   // [512,384]
  const float* K0 = (const float*)d_in[1];  // [384,384]
  float* out = (float*)d_out;               // [512,384]

  float* G = (float*)d_ws;                  // 512*512
  float* M0 = G + 512 * 512;                // 512*384
  float* u = M0 + 512 * 384;                // 512
  float* W = u + 512;                       // 512
  float* gS = W + 512;                      // 1
  float* Kpart = gS + 1;                    // 64

  gemm_nt<<<dim3(16, 16), 256, 0, stream>>>(E, E, G, 512, 384);     // G = E E^T
  gemm_nn<<<dim3(12, 16), 256, 0, stream>>>(E, K0, M0, 384, 384);   // M0 = E K0
  prep_kernel<<<192, 256, 0, stream>>>(E, M0, K0, u, Kpart);
  scan_kernel<<<1, 128, 0, stream>>>(G, u, Kpart, W, gS);
  final_gemm<<<dim3(12, 16), 256, 0, stream>>>(G, E, M0, W, gS, out);
}

// Round 13
// 415.044 us; speedup vs baseline: 1.5868x; 1.0361x over previous
//
#include <hip/hip_runtime.h>

// ---------------------------------------------------------------------------
// SemanticMemoryLatentSpace, fully factored (see R7 header).
// R12: DECOUPLED two-wave scan, ZERO barriers in the main loop (R11 showed
// barrier vmcnt/lgkmcnt drains eat ~2000cyc/round).
//   wave0: 8-step rounds: col reads, chain (gx/tr/ren from LDS tables),
//          in-register patching, RAW atomics, own G prefetch, own journal,
//          t=256 rebuild. Publishes {bnew,idx,nov} per step to a full-depth
//          ring + release flag. Never waits on wave1.
//   wave1: polls flag (acquire+s_sleep), runs n2/g/wh lag chain, maintains
//          q over ALL 512 cols (no rebuild), writes wh/Wout/gOut.
// Arithmetic op-identical to R8 -> same output.
// ---------------------------------------------------------------------------

#define A_BOOSTF 0.012247448713915891f // 1.5*alpha (growth==0 always)

template <int CTRL>
__device__ __forceinline__ float dpp_f(float x) {
  return __int_as_float(
      __builtin_amdgcn_mov_dpp(__float_as_int(x), CTRL, 0xf, 0xf, true));
}
template <int CTRL>
__device__ __forceinline__ unsigned dpp_u(unsigned x) {
  return (unsigned)__builtin_amdgcn_mov_dpp((int)x, CTRL, 0xf, 0xf, true);
}
__device__ __forceinline__ float rdlane_f(float x, int l) {
  return __int_as_float(__builtin_amdgcn_readlane(__float_as_int(x), l));
}
__device__ __forceinline__ unsigned rdlane_u(unsigned x, int l) {
  return (unsigned)__builtin_amdgcn_readlane((int)x, l);
}
__device__ __forceinline__ float wave_sum64(float v) {
  v += dpp_f<0xB1>(v);
  v += dpp_f<0x4E>(v);
  v += dpp_f<0x124>(v);
  v += dpp_f<0x128>(v);
  return (rdlane_f(v, 0) + rdlane_f(v, 16)) + (rdlane_f(v, 32) + rdlane_f(v, 48));
}
__device__ __forceinline__ unsigned sortable(float v) {
  unsigned u = __float_as_uint(v);
  return u ^ (unsigned)(((int)u >> 31) | 0x80000000);
}
__device__ __forceinline__ float unsortable(unsigned x) {
  unsigned u = (x & 0x80000000u) ? (x ^ 0x80000000u) : ~x;
  return __uint_as_float(u);
}
__device__ __forceinline__ unsigned wave_umax64(unsigned v) {
  v = max(v, dpp_u<0xB1>(v));
  v = max(v, dpp_u<0x4E>(v));
  v = max(v, dpp_u<0x124>(v));
  v = max(v, dpp_u<0x128>(v));
  return max(max(rdlane_u(v, 0), rdlane_u(v, 16)),
             max(rdlane_u(v, 32), rdlane_u(v, 48)));
}

// ---------------- generic 32x32-tile fp32 GEMMs -----------------------------
__global__ __launch_bounds__(256) void gemm_nt(const float* __restrict__ A,
                                               const float* __restrict__ B,
                                               float* __restrict__ C,
                                               int N, int K) {
  __shared__ float As[32][33];
  __shared__ float Bs[32][33];
  int bx = blockIdx.x, by = blockIdx.y;
  int tid = threadIdx.x;
  int tx = tid & 15, ty = tid >> 4;
  float a00 = 0.f, a01 = 0.f, a10 = 0.f, a11 = 0.f;
  for (int k0 = 0; k0 < K; k0 += 32) {
    for (int l = tid; l < 1024; l += 256) {
      int r = l >> 5, c = l & 31;
      As[r][c] = A[(by * 32 + r) * K + k0 + c];
      Bs[r][c] = B[(bx * 32 + r) * K + k0 + c];
    }
    __syncthreads();
#pragma unroll
    for (int k = 0; k < 32; ++k) {
      float x0 = As[2 * ty][k], x1 = As[2 * ty + 1][k];
      float y0 = Bs[2 * tx][k], y1 = Bs[2 * tx + 1][k];
      a00 += x0 * y0; a01 += x0 * y1; a10 += x1 * y0; a11 += x1 * y1;
    }
    __syncthreads();
  }
  int i = by * 32 + 2 * ty, jj = bx * 32 + 2 * tx;
  C[i * N + jj] = a00;           C[i * N + jj + 1] = a01;
  C[(i + 1) * N + jj] = a10;     C[(i + 1) * N + jj + 1] = a11;
}

__global__ __launch_bounds__(256) void gemm_nn(const float* __restrict__ A,
                                               const float* __restrict__ B,
                                               float* __restrict__ C,
                                               int N, int K) {
  __shared__ float As[32][33];
  __shared__ float Bs[32][33];
  int bx = blockIdx.x, by = blockIdx.y;
  int tid = threadIdx.x;
  int tx = tid & 15, ty = tid >> 4;
  float a00 = 0.f, a01 = 0.f, a10 = 0.f, a11 = 0.f;
  for (int k0 = 0; k0 < K; k0 += 32) {
    for (int l = tid; l < 1024; l += 256) {
      int r = l >> 5, c = l & 31;
      As[r][c] = A[(by * 32 + r) * K + k0 + c];
      Bs[r][c] = B[(k0 + r) * N + bx * 32 + c];
    }
    __syncthreads();
#pragma unroll
    for (int k = 0; k < 32; ++k) {
      float x0 = As[2 * ty][k], x1 = As[2 * ty + 1][k];
      float y0 = Bs[k][2 * tx], y1 = Bs[k][2 * tx + 1];
      a00 += x0 * y0; a01 += x0 * y1; a10 += x1 * y0; a11 += x1 * y1;
    }
    __syncthreads();
  }
  int i = by * 32 + 2 * ty, jj = bx * 32 + 2 * tx;
  C[i * N + jj] = a00;           C[i * N + jj + 1] = a01;
  C[(i + 1) * N + jj] = a10;     C[(i + 1) * N + jj + 1] = a11;
}

__global__ __launch_bounds__(256) void final_gemm(const float* __restrict__ G,
                                                  const float* __restrict__ E,
                                                  const float* __restrict__ M0,
                                                  const float* __restrict__ W,
                                                  const float* __restrict__ gS,
                                                  float* __restrict__ out) {
  __shared__ float As[32][33];
  __shared__ float Bs[32][33];
  int bx = blockIdx.x, by = blockIdx.y;
  int tid = threadIdx.x;
  int tx = tid & 15, ty = tid >> 4;
  float a00 = 0.f, a01 = 0.f, a10 = 0.f, a11 = 0.f;
  for (int k0 = 0; k0 < 512; k0 += 32) {
    for (int l = tid; l < 1024; l += 256) {
      int r = l >> 5, c = l & 31;
      As[r][c] = G[(by * 32 + r) * 512 + k0 + c] * W[k0 + c];
      Bs[r][c] = E[(k0 + r) * 384 + bx * 32 + c];
    }
    __syncthreads();
#pragma unroll
    for (int k = 0; k < 32; ++k) {
      float x0 = As[2 * ty][k], x1 = As[2 * ty + 1][k];
      float y0 = Bs[k][2 * tx], y1 = Bs[k][2 * tx + 1];
      a00 += x0 * y0; a01 += x0 * y1; a10 += x1 * y0; a11 += x1 * y1;
    }
    __syncthreads();
  }
  float gv = gS[0];
  int i = by * 32 + 2 * ty, jj = bx * 32 + 2 * tx;
  out[i * 384 + jj]         = gv * M0[i * 384 + jj]         + a00;
  out[i * 384 + jj + 1]     = gv * M0[i * 384 + jj + 1]     + a01;
  out[(i + 1) * 384 + jj]     = gv * M0[(i + 1) * 384 + jj]     + a10;
  out[(i + 1) * 384 + jj + 1] = gv * M0[(i + 1) * 384 + jj + 1] + a11;
}

__global__ __launch_bounds__(256) void prep_kernel(const float* __restrict__ E,
                                                   const float* __restrict__ M0,
                                                   const float* __restrict__ K0,
                                                   float* __restrict__ u,
                                                   float* __restrict__ Kpart) {
  __shared__ double wr[4];
  int b = blockIdx.x;
  int tid = threadIdx.x, lane = tid & 63, wv = tid >> 6;
  if (b < 128) {
    int row = b * 4 + wv;
    const float4* e4 = (const float4*)(E + row * 384);
    const float4* m4 = (const float4*)(M0 + row * 384);
    float p = 0.f;
    for (int i = lane; i < 96; i += 64) {
      float4 a = e4[i], bb = m4[i];
      p += a.x * bb.x + a.y * bb.y + a.z * bb.z + a.w * bb.w;
    }
#pragma unroll
    for (int off = 32; off; off >>= 1) p += __shfl_down(p, off);
    if (lane == 0) u[row] = p;
  } else {
    int cb = b - 128;
    const float* p = K0 + cb * 2304 + tid * 9;
    double acc = 0.0;
#pragma unroll
    for (int i = 0; i < 9; ++i) { double v = (double)p[i]; acc += v * v; }
#pragma unroll
    for (int off = 32; off; off >>= 1) acc += __shfl_down(acc, off);
    if (lane == 0) wr[wv] = acc;
    __syncthreads();
    if (tid == 0) Kpart[cb] = (float)(wr[0] + wr[1] + wr[2] + wr[3]);
  }
}

// ---------------- decoupled two-wave scan -----------------------------------
__global__ __launch_bounds__(128) void scan_kernel(const float* __restrict__ G,
                                                   const float* __restrict__ u,
                                                   const float* __restrict__ Kpart,
                                                   float* __restrict__ Wout,
                                                   float* __restrict__ gOut) {
  __shared__ float RAW[100 * 257];     // 102800 B, rows = clusters (<100)
  __shared__ float gx_tbl[512 * 8];    // [t][d]: d=0 -> G[t][t], d>=1 -> G[t][t+d]
  __shared__ float ren_tbl[512];       // rcp(sqrt(G[t][t]))
  __shared__ float u_sh[512];
  __shared__ float wh_sh[512];
  __shared__ float2 JRN[512];          // wave0 journal {bnew, idxbits}
  __shared__ float4 RING[512];         // full-depth ring {bnew, idxbits, nov, 0}
  __shared__ int FLAG;

  const int tid = threadIdx.x;
  const int wid = tid >> 6;
  const int lane = tid & 63;

  // ---- cooperative init ----
  float4 z4 = {0.f, 0.f, 0.f, 0.f};
  for (int i = tid; i < 6425; i += 128) ((float4*)RAW)[i] = z4;
  for (int tt = tid; tt < 512; tt += 128) {
    float trv = G[tt * 512 + tt];
    gx_tbl[tt * 8] = trv;
#pragma unroll
    for (int d = 1; d < 8; ++d)
      gx_tbl[tt * 8 + d] = (tt + d < 512) ? G[tt * 512 + tt + d] : 0.f;
    ren_tbl[tt] = __builtin_amdgcn_rcpf(__builtin_amdgcn_sqrtf(trv));
  }
  if (tid < 128) ((float4*)u_sh)[tid] = ((const float4*)u)[tid];
  if (tid == 0) FLAG = 0;
  __syncthreads();

  if (wid == 0) {
    // ================== WAVE 0: decision wave ==================
    float d0 = 1.f, d1 = 1.f, cn0 = 0.f, cn1 = 0.f, s0 = 0.f, s1 = 0.f;
    int nact = 0;
    float r0[8], r1[8];
#pragma unroll
    for (int j = 0; j < 8; ++j) { r0[j] = 0.f; r1[j] = 0.f; }

    float bufA[8][4], bufB[8][4];
#pragma unroll
    for (int k = 0; k < 8; ++k)
#pragma unroll
      for (int m = 0; m < 4; ++m)
        bufA[k][m] = G[k * 512 + m * 64 + lane];

#define W0_ROUND(R_, CUR, NXT)                                                 \
    {                                                                          \
      const int t = 8 * (R_);                                                  \
      const int c = t & 255;                                                   \
      const int tn = t + 8;                                                    \
      if (tn < 512) {                                                          \
        const int nb = tn & ~255;                                              \
        _Pragma("unroll") for (int k = 0; k < 8; ++k)                          \
          _Pragma("unroll") for (int m = 0; m < 4; ++m)                        \
            NXT[k][m] = G[(tn + k) * 512 + nb + m * 64 + lane];                \
      }                                                                        \
      if (t == 256) {                                                          \
        for (int i = lane; i < 6425; i += 64) ((float4*)RAW)[i] = z4;          \
        __builtin_amdgcn_sched_barrier(0);                                     \
        const float* Gb = G + 256;                                             \
        float A[4][4], Bv[4][4];                                               \
        float2 SA[4], SB[4];                                                   \
        _Pragma("unroll") for (int j = 0; j < 4; ++j) {                        \
          _Pragma("unroll") for (int m = 0; m < 4; ++m)                        \
            A[j][m] = Gb[j * 512 + m * 64 + lane];                             \
          SA[j] = JRN[j];                                                      \
        }                                                                      \
        for (int s = 0; s < 256; s += 8) {                                     \
          _Pragma("unroll") for (int j = 0; j < 4; ++j) {                      \
            _Pragma("unroll") for (int m = 0; m < 4; ++m)                      \
              Bv[j][m] = Gb[(s + 4 + j) * 512 + m * 64 + lane];                \
            SB[j] = JRN[s + 4 + j];                                            \
          }                                                                    \
          _Pragma("unroll") for (int j = 0; j < 4; ++j) {                      \
            float bh = SA[j].x; int id = __float_as_int(SA[j].y);              \
            _Pragma("unroll") for (int m = 0; m < 4; ++m)                      \
              atomicAdd(&RAW[id * 257 + m * 64 + lane], bh * A[j][m]);         \
          }                                                                    \
          if (s + 8 < 256) {                                                   \
            _Pragma("unroll") for (int j = 0; j < 4; ++j) {                    \
              _Pragma("unroll") for (int m = 0; m < 4; ++m)                    \
                A[j][m] = Gb[(s + 8 + j) * 512 + m * 64 + lane];               \
              SA[j] = JRN[s + 8 + j];                                          \
            }                                                                  \
          }                                                                    \
          _Pragma("unroll") for (int j = 0; j < 4; ++j) {                      \
            float bh = SB[j].x; int id = __float_as_int(SB[j].y);              \
            _Pragma("unroll") for (int m = 0; m < 4; ++m)                      \
              atomicAdd(&RAW[id * 257 + m * 64 + lane], bh * Bv[j][m]);        \
          }                                                                    \
        }                                                                      \
        __builtin_amdgcn_sched_barrier(0);                                     \
        _Pragma("unroll") for (int j = 0; j < 8; ++j)                          \
          r0[j] = RAW[lane * 257 + j];                                         \
        if (lane < 36) {                                                       \
          _Pragma("unroll") for (int j = 0; j < 8; ++j)                        \
            r1[j] = RAW[(lane + 64) * 257 + j];                                \
        }                                                                      \
        __builtin_amdgcn_sched_barrier(0);                                     \
      }                                                                        \
      float trk[8], renk[8], gxv[8][8];                                        \
      _Pragma("unroll") for (int k = 0; k < 8; ++k) {                          \
        trk[k] = gx_tbl[(t + k) * 8];                                          \
        renk[k] = ren_tbl[t + k];                                              \
        _Pragma("unroll") for (int j = k + 1; j < 8; ++j)                      \
          gxv[k][j] = gx_tbl[(t + k) * 8 + (j - k)];                           \
      }                                                                        \
      float bnewA[8], novA[8];                                                 \
      int idxA[8];                                                             \
      _Pragma("unroll") for (int k = 0; k < 8; ++k) {                          \
        float v0 = (lane < nact) ? s0 * renk[k] * r0[k] : -2.f;                \
        float v1 = (lane + 64 < nact) ? s1 * renk[k] * r1[k] : -2.f;           \
        unsigned pk0 = (sortable(v0) & ~127u) | (unsigned)(127 - lane);        \
        unsigned pk1 = (sortable(v1) & ~127u) | (unsigned)(63 - lane);         \
        unsigned P = wave_umax64(max(pk0, pk1));                               \
        int imax = 127 - (int)(P & 127u);                                      \
        float M = unsortable(P & ~127u);                                       \
        float nov = (nact == 0) ? 1.f : fminf(1.f, fmaxf(0.f, 1.f - M * M));   \
        int create = (nov > 0.7f && nact < 100) ? 1 : 0;                       \
        const int idxs = create ? nact : imax;                                 \
        const int cl = idxs & 63, hi = idxs >> 6;                              \
        float dcA = create ? 1.f : 0.95f * d0;                                 \
        float dcB = create ? 1.f : 0.95f * d1;                                 \
        float ccA = create ? trk[k]                                            \
                           : (0.9025f * cn0 + 0.095f * (d0 * r0[k]) +          \
                              0.0025f * trk[k]);                               \
        float ccB = create ? trk[k]                                            \
                           : (0.9025f * cn1 + 0.095f * (d1 * r1[k]) +          \
                              0.0025f * trk[k]);                               \
        float scA = dcA * __builtin_amdgcn_rcpf(__builtin_amdgcn_sqrtf(ccA));  \
        float scB = dcB * __builtin_amdgcn_rcpf(__builtin_amdgcn_sqrtf(ccB));  \
        bool own0 = (lane == cl) && (hi == 0);                                 \
        bool own1 = (lane == cl) && (hi == 1);                                 \
        d0 = own0 ? dcA : d0; cn0 = own0 ? ccA : cn0; s0 = own0 ? scA : s0;    \
        d1 = own1 ? dcB : d1; cn1 = own1 ? ccB : cn1; s1 = own1 ? scB : s1;    \
        float bnew = create ? 1.f                                              \
                            : 0.05f * __builtin_amdgcn_rcpf(                   \
                                          rdlane_f(hi ? dcB : dcA, cl));       \
        nact += create;                                                        \
        float pb0 = own0 ? bnew : 0.f, pb1 = own1 ? bnew : 0.f;                \
        _Pragma("unroll") for (int j = k + 1; j < 8; ++j) {                    \
          r0[j] += pb0 * gxv[k][j];                                            \
          r1[j] += pb1 * gxv[k][j];                                            \
        }                                                                      \
        bnewA[k] = bnew; novA[k] = nov; idxA[k] = idxs;                        \
      }                                                                        \
      if (lane == 0) {                                                         \
        _Pragma("unroll") for (int k = 0; k < 8; ++k) {                        \
          float2 j2; j2.x = bnewA[k]; j2.y = __int_as_float(idxA[k]);          \
          JRN[t + k] = j2;                                                     \
          float4 r4; r4.x = bnewA[k]; r4.y = __int_as_float(idxA[k]);          \
          r4.z = novA[k]; r4.w = 0.f;                                          \
          RING[t + k] = r4;                                                    \
        }                                                                      \
        __hip_atomic_store(&FLAG, (R_) + 1, __ATOMIC_RELEASE,                  \
                           __HIP_MEMORY_SCOPE_WORKGROUP);                      \
      }                                                                        \
      _Pragma("unroll") for (int k = 0; k < 8; ++k)                            \
        _Pragma("unroll") for (int m = 0; m < 4; ++m)                          \
          if (m * 64 + 63 >= c)                                                \
            atomicAdd(&RAW[idxA[k] * 257 + m * 64 + lane],                     \
                      bnewA[k] * CUR[k][m]);                                   \
      const int cnx = tn & 255;                                                \
      if (tn < 512 && cnx != 0) {                                              \
        _Pragma("unroll") for (int j = 0; j < 8; ++j)                          \
          r0[j] = RAW[lane * 257 + cnx + j];                                   \
        if (lane < 36) {                                                       \
          _Pragma("unroll") for (int j = 0; j < 8; ++j)                        \
            r1[j] = RAW[(lane + 64) * 257 + cnx + j];                          \
        }                                                                      \
      }                                                                        \
    }

    for (int R = 0; R < 64; R += 2) {
      W0_ROUND(R, bufA, bufB)
      W0_ROUND(R + 1, bufB, bufA)
    }
#undef W0_ROUND
  } else {
    // ================== WAVE 1: lag wave ==================
    float q8[8];
#pragma unroll
    for (int gI = 0; gI < 8; ++gI) q8[gI] = 0.f;
    float n2 = wave_sum64(Kpart[lane]);
    float g = 1.f, ginv = 1.f;

    for (int R = 0; R < 64; ++R) {
      const int t = 8 * R;
      // issue this round's G-row loads (consumed at round end)
      float B[8][8];
#pragma unroll
      for (int k = 0; k < 8; ++k)
#pragma unroll
        for (int gI = 0; gI < 8; ++gI)
          B[k][gI] = G[(t + k) * 512 + gI * 64 + lane];

      while (__hip_atomic_load(&FLAG, __ATOMIC_ACQUIRE,
                               __HIP_MEMORY_SCOPE_WORKGROUP) <= R)
        __builtin_amdgcn_s_sleep(1);

      float4 rgv[8];
#pragma unroll
      for (int k = 0; k < 8; ++k) rgv[k] = RING[t + k];

      float trm[8], gxw[8][8];
#pragma unroll
      for (int m = 0; m < 8; ++m) {
        trm[m] = gx_tbl[(t + m) * 8];
#pragma unroll
        for (int j = m + 1; j < 8; ++j)
          gxw[m][j] = gx_tbl[(t + m) * 8 + (j - m)];
      }
      float4 uuA = *(const float4*)&u_sh[t];
      float4 uuB = *(const float4*)&u_sh[t + 4];
      float um[8] = {uuA.x, uuA.y, uuA.z, uuA.w, uuB.x, uuB.y, uuB.z, uuB.w};

      const int grp = t >> 6;
      float qsel = q8[0];
#pragma unroll
      for (int gI = 1; gI < 8; ++gI) qsel = (grp == gI) ? q8[gI] : qsel;
      float qeff[8];
#pragma unroll
      for (int k = 0; k < 8; ++k) qeff[k] = rdlane_f(qsel, (t & 63) + k);

      float wh[8];
#pragma unroll
      for (int m = 0; m < 8; ++m) {
        float nov = rgv[m].z;
        float iw = nov * __builtin_amdgcn_sqrtf(nov);
        float psc = 384.0f * __builtin_amdgcn_rcpf(fmaxf(trm[m], 1e-8f));
        float ccf = A_BOOSTF * iw * psc;
        float qv = g * (um[m] + qeff[m]);
        float n2n = n2 + 2.f * ccf * qv + ccf * ccf * trm[m] * trm[m];
        float kn = __builtin_amdgcn_sqrtf(n2n);
        float fct = (kn > 50.f) ? 50.f * __builtin_amdgcn_rcpf(kn) : 1.f;
        float fiv = (kn > 50.f) ? kn * 0.02f : 1.f;
        wh[m] = ccf * ginv;
        n2 = n2n * fct * fct; g *= fct; ginv *= fiv;
#pragma unroll
        for (int j = m + 1; j < 8; ++j)
          qeff[j] += wh[m] * gxw[m][j] * gxw[m][j];
      }

      if (lane == 0) {
#pragma unroll
        for (int m = 0; m < 8; ++m) wh_sh[t + m] = wh[m];
      }
#pragma unroll
      for (int gI = 0; gI < 8; ++gI)
#pragma unroll
        for (int k = 0; k < 8; ++k)
          q8[gI] += wh[k] * B[k][gI] * B[k][gI];
    }

    for (int s2 = lane; s2 < 512; s2 += 64) Wout[s2] = wh_sh[s2] * g;
    if (lane == 0) gOut[0] = g;
  }
}

extern "C" void kernel_launch(void* const* d_in, const int* in_sizes, int n_in,
                              void* d_out, int out_size, void* d_ws,
                              size_t ws_size, hipStream_t stream) {
  const float* E = (const float*)d_in[0];   // [512,384]
  const float* K0 = (const float*)d_in[1];  // [384,384]
  float* out = (float*)d_out;               // [512,384]

  float* G = (float*)d_ws;                  // 512*512
  float* M0 = G + 512 * 512;                // 512*384
  float* u = M0 + 512 * 384;                // 512
  float* W = u + 512;                       // 512
  float* gS = W + 512;                      // 1
  float* Kpart = gS + 1;                    // 64

  gemm_nt<<<dim3(16, 16), 256, 0, stream>>>(E, E, G, 512, 384);     // G = E E^T
  gemm_nn<<<dim3(12, 16), 256, 0, stream>>>(E, K0, M0, 384, 384);   // M0 = E K0
  prep_kernel<<<192, 256, 0, stream>>>(E, M0, K0, u, Kpart);
  scan_kernel<<<1, 128, 0, stream>>>(G, u, Kpart, W, gS);
  final_gemm<<<dim3(12, 16), 256, 0, stream>>>(G, E, M0, W, gS, out);
}